// Round 10
// baseline (279.849 us; speedup 1.0000x reference)
//
#include <hip/hip_runtime.h>
#include <math.h>

typedef unsigned short ushort_t;
typedef __attribute__((ext_vector_type(8))) short bf16x8;
typedef __attribute__((ext_vector_type(4))) float f32x4;

constexpr int kD      = 768;
constexpr int kNH     = 12;
constexpr int kDK     = 64;
constexpr int kFF     = 3072;
constexpr int kL      = 1024;
constexpr int kRows   = 2048;     // B * L
constexpr float kEPS  = 1e-5f;

__device__ __forceinline__ ushort_t f2bf(float f) {
    union { float f; unsigned u; } v; v.f = f;
    unsigned r = (v.u + 0x7fffu + ((v.u >> 16) & 1u)) >> 16;
    return (ushort_t)r;
}
__device__ __forceinline__ float bf2f(ushort_t u) {
    union { unsigned u; float f; } v; v.u = ((unsigned)u) << 16; return v.f;
}

#define GL_LDS(gp, lp) __builtin_amdgcn_global_load_lds( \
    (const __attribute__((address_space(1))) void*)(gp), \
    (__attribute__((address_space(3))) void*)(lp), 16, 0, 0)

// ---------------------------------------------------------------------------
// bf16 MFMA GEMM body: 128x128 tile, BK=32, 4 waves, double-buffered LDS.
// Epilogue modes:
//   OUTMODE 0: fp32 direct stores (split-K partials).
//   OUTMODE 1: bf16 via LDS staging -> coalesced uint4 row stores.
//   OUTMODE 2: bf16 transposed via LDS -> V^T tile direct to vt, with the
//              attn-fragment key permutation folded in (see attn kernel).
// LDS supplied by caller: >= 17408 ushorts.  Staging tile [128][136].
// ---------------------------------------------------------------------------
template<int RELU, int OUTMODE, int ADDBIAS>
__device__ __forceinline__ void gemm_body(const ushort_t* __restrict__ A,
                                          const ushort_t* __restrict__ WT,
                                          const float* __restrict__ bias,
                                          void* __restrict__ Cout,
                                          int N, int K, int row0, int col0,
                                          int kbeg, int kend, ushort_t* lds)
{
    const int tid  = threadIdx.x;
    const int lane = tid & 63;
    const int wave = tid >> 6;
    const int wrow = (wave & 1) * 64;
    const int wcol = (wave >> 1) * 64;

    const int srow = wave * 16 + (lane >> 2);
    const int sk   = (lane & 3) * 8;
    const ushort_t* ga0 = A  + (size_t)(row0 + srow)      * K + sk;
    const ushort_t* ga1 = A  + (size_t)(row0 + srow + 64) * K + sk;
    const ushort_t* gb0 = WT + (size_t)(col0 + srow)      * K + sk;
    const ushort_t* gb1 = WT + (size_t)(col0 + srow + 64) * K + sk;

    const int wo = wave * 512;
    const int fl = lane & 15, fq = lane >> 4;

    f32x4 acc[4][4] = {};

    {
        ushort_t* b0 = lds;
        GL_LDS(ga0 + kbeg, b0 + wo);
        GL_LDS(ga1 + kbeg, b0 + 2048 + wo);
        GL_LDS(gb0 + kbeg, b0 + 4096 + wo);
        GL_LDS(gb1 + kbeg, b0 + 4096 + 2048 + wo);
    }
    __syncthreads();

    int cur = 0;
    for (int k0 = kbeg; k0 < kend; k0 += 32) {
        ushort_t* bs = lds + (cur ? 8192 : 0);
        ushort_t* bn = lds + (cur ? 0 : 8192);

        if (k0 + 32 < kend) {
            GL_LDS(ga0 + k0 + 32, bn + wo);
            GL_LDS(ga1 + k0 + 32, bn + 2048 + wo);
            GL_LDS(gb0 + k0 + 32, bn + 4096 + wo);
            GL_LDS(gb1 + k0 + 32, bn + 4096 + 2048 + wo);
        }

        bf16x8 av[4], bv[4];
        #pragma unroll
        for (int i = 0; i < 4; ++i) {
            av[i] = *(const bf16x8*)(bs + (wrow + i * 16 + fl) * 32 + fq * 8);
            bv[i] = *(const bf16x8*)(bs + 4096 + (wcol + i * 16 + fl) * 32 + fq * 8);
        }
        #pragma unroll
        for (int mi = 0; mi < 4; ++mi)
            #pragma unroll
            for (int ni = 0; ni < 4; ++ni)
                acc[mi][ni] = __builtin_amdgcn_mfma_f32_16x16x32_bf16(
                    av[mi], bv[ni], acc[mi][ni], 0, 0, 0);

        __syncthreads();
        cur ^= 1;
    }

    if (OUTMODE == 0) {
        #pragma unroll
        for (int mi = 0; mi < 4; ++mi) {
            const int m = wrow + mi * 16 + fq * 4;
            #pragma unroll
            for (int ni = 0; ni < 4; ++ni) {
                const int n = wcol + ni * 16 + fl;
                const float bb = ADDBIAS ? bias[col0 + n] : 0.f;
                #pragma unroll
                for (int r = 0; r < 4; ++r) {
                    float v = acc[mi][ni][r] + bb;
                    if (RELU) v = fmaxf(v, 0.f);
                    ((float*)Cout)[(size_t)(row0 + m + r) * N + col0 + n] = v;
                }
            }
        }
    } else {
        ushort_t* T = lds;            // [128][136] staging tile
        #pragma unroll
        for (int mi = 0; mi < 4; ++mi) {
            const int m = wrow + mi * 16 + fq * 4;
            #pragma unroll
            for (int ni = 0; ni < 4; ++ni) {
                const int n = wcol + ni * 16 + fl;
                const float bb = ADDBIAS ? bias[col0 + n] : 0.f;
                #pragma unroll
                for (int r = 0; r < 4; ++r) {
                    float v = acc[mi][ni][r] + bb;
                    if (RELU) v = fmaxf(v, 0.f);
                    if (OUTMODE == 1) T[(m + r) * 136 + n] = f2bf(v);
                    else              T[n * 136 + (m + r)] = f2bf(v);
                }
            }
        }
        __syncthreads();
        const int row = tid >> 1;     // token (mode1) / feature (mode2)
        const int seg = tid & 1;      // 64-elem half
        const ushort_t* sp = T + row * 136 + seg * 64;
        if (OUTMODE == 1) {
            ushort_t* dp = (ushort_t*)Cout + (size_t)(row0 + row) * N + col0 + seg * 64;
            #pragma unroll
            for (int i = 0; i < 8; ++i)
                *(uint4*)(dp + i * 8) = *(const uint4*)(sp + i * 8);
        } else {
            const int bb2 = row0 >> 10;            // batch (tiles never straddle)
            const int c   = col0 + row;            // global feature 0..767
            const int vtr = (bb2 * kNH + (c >> 6)) * kDK + (c & 63);
            ushort_t* dp = (ushort_t*)Cout + (size_t)vtr * kL + (row0 & 1023) + seg * 64;
            // permuted gather: output position p (within each 32-token block)
            // holds actual token pi(p); granule (4-token) map pg -> ga:
            //   ga = (pg&1)*4 + (pg>>1)
            uint2 w[16];
            #pragma unroll
            for (int g = 0; g < 16; ++g) {
                const int h32 = g >> 3, pg = g & 7;
                const int srcTok = h32 * 32 + ((pg & 1) * 4 + (pg >> 1)) * 4;
                w[g] = *(const uint2*)(sp + srcTok);
            }
            #pragma unroll
            for (int i = 0; i < 8; ++i) {
                uint4 o; o.x = w[2*i].x; o.y = w[2*i].y;
                o.z = w[2*i+1].x; o.w = w[2*i+1].y;
                *(uint4*)(dp + i * 8) = o;
            }
        }
    }
}

template<int RELU, int OUTMODE>
__global__ __launch_bounds__(256)
void gemm_kernel(const ushort_t* __restrict__ A, const ushort_t* __restrict__ WT,
                 const float* __restrict__ bias, void* __restrict__ Cout,
                 int N, int K)
{
    __shared__ ushort_t lds[17408];
    gemm_body<RELU, OUTMODE, 1>(A, WT, bias, Cout, N, K,
                                blockIdx.y * 128, blockIdx.x * 128, 0, K, lds);
}

__global__ __launch_bounds__(256)
void gemm_splitk_kernel(const ushort_t* __restrict__ A, const ushort_t* __restrict__ WT,
                        float* __restrict__ parts, int N, int K, int kslice)
{
    __shared__ ushort_t lds[17408];
    const int z = blockIdx.z;
    float* out = parts + (size_t)z * kRows * N;
    gemm_body<0, 0, 0>(A, WT, nullptr, out, N, K,
                       blockIdx.y * 128, blockIdx.x * 128,
                       z * kslice, (z + 1) * kslice, lds);
}

// ---------------------------------------------------------------------------
// Weight transpose tile: W[K][N] fp32 -> WT[N][K] bf16, 64x64 tile at (kt,nt).
// ---------------------------------------------------------------------------
__device__ __forceinline__ void wt_tile(const float* __restrict__ src,
                                        ushort_t* __restrict__ dst,
                                        int K, int N, int kt, int nt,
                                        float (*T)[65], int tid)
{
    #pragma unroll
    for (int i = 0; i < 4; ++i) {
        const int e = tid + i * 256;
        const int r = e >> 4;
        const int c = (e & 15) * 4;
        const float4 f = *(const float4*)&src[(size_t)(kt + r) * N + nt + c];
        T[c + 0][r] = f.x; T[c + 1][r] = f.y; T[c + 2][r] = f.z; T[c + 3][r] = f.w;
    }
    __syncthreads();
    #pragma unroll
    for (int i = 0; i < 4; ++i) {
        const int e = tid + i * 256;
        const int n = e >> 4;
        const int kc = (e & 15) * 4;
        ushort4 o;
        o.x = f2bf(T[n][kc + 0]); o.y = f2bf(T[n][kc + 1]);
        o.z = f2bf(T[n][kc + 2]); o.w = f2bf(T[n][kc + 3]);
        *(ushort4*)&dst[(size_t)(nt + n) * K + kt + kc] = o;
    }
}

// ---------------------------------------------------------------------------
// prep: ROUND-10 — ALL weight transposes live here now (they have no input
// dependencies; consumers are dispatches 4+).  Previously Wo/W1/W2 tiles sat
// at the END of the attn dispatch, where their strided fp32 HBM reads formed
// a ~25 us tail that four different attn restructures (r1/r2/r8/r9, all
// 55+-2 us) could not move — the invariant was the wt tail, not attn.
//   blocks 0..431    : Wq,Wk,Wv transposes (144 tiles each)
//   blocks 432..575  : Wo transpose (144)
//   blocks 576..1151 : W1 transpose (576)
//   blocks 1152..1727: W2 transpose (576)
//   blocks 1728..3263: src fp32->bf16 (1536)
// ---------------------------------------------------------------------------
__global__ __launch_bounds__(256)
void prep_kernel(const float* __restrict__ Wq, const float* __restrict__ Wk,
                 const float* __restrict__ Wv,
                 ushort_t* wqT, ushort_t* wkT, ushort_t* wvT,
                 const float* __restrict__ src, ushort_t* __restrict__ sb,
                 const float* __restrict__ Wo, const float* __restrict__ W1,
                 const float* __restrict__ W2,
                 ushort_t* woT, ushort_t* w1T, ushort_t* w2T)
{
    __shared__ float T[64][65];
    const int bid = blockIdx.x;
    const int tid = threadIdx.x;

    if (bid < 432) {
        const int wz = bid / 144, t = bid - wz * 144;
        const float* s = (wz == 0) ? Wq : (wz == 1) ? Wk : Wv;
        ushort_t*   d = (wz == 0) ? wqT : (wz == 1) ? wkT : wvT;
        wt_tile(s, d, kD, kD, (t % 12) * 64, (t / 12) * 64, T, tid);
    } else if (bid < 576) {
        const int t = bid - 432;
        wt_tile(Wo, woT, kD, kD, (t % 12) * 64, (t / 12) * 64, T, tid);
    } else if (bid < 1152) {
        const int t = bid - 576;
        wt_tile(W1, w1T, kD, kFF, (t % 12) * 64, (t / 12) * 64, T, tid);
    } else if (bid < 1728) {
        const int t = bid - 1152;
        wt_tile(W2, w2T, kFF, kD, (t % 48) * 64, (t / 48) * 64, T, tid);
    } else {
        const int i = (bid - 1728) * 256 + tid;
        const float4 f = ((const float4*)src)[i];
        ushort4 o;
        o.x = f2bf(f.x); o.y = f2bf(f.y); o.z = f2bf(f.z); o.w = f2bf(f.w);
        ((ushort4*)sb)[i] = o;
    }
}

// ---------------------------------------------------------------------------
// Shared-memory layouts for the fused kernels.
// ---------------------------------------------------------------------------
struct BiasSmem {                 // 27312 B
    float P[32][16];              // [u] = {A,B,C,0, W2[0..11]}
    float pb2l[12];
    float qxl[16], qyl[16], kxl[64], kyl[64];
    ushort_t Btile[12 * 1024];
};
struct AttnSmem {                 // 8960 B (Ob rows padded 64->68:
    ushort_t Ob[4][16][68];       //  stride 136 B spreads the 4 fq-lanes to
    float    Ll[4][16];           //  banks +0/8/16/24 -> conflict-free)
};

// ---------------------------------------------------------------------------
// Relative-position bias tile body (-4 shift folded).
// Thread remap (q=tid>>4, fq2=(tid>>2)&3, n=tid&3): 4 outputs land in 4
// CONSECUTIVE Btile slots -> 12 ushort4 stores (bank-balanced).
// Slot layout matches the swapped-QK attention fragment.
// ---------------------------------------------------------------------------
__device__ __forceinline__ void bias_body(int bid, BiasSmem& S,
                 const float* __restrict__ sx, const float* __restrict__ sy,
                 const float* __restrict__ P1, const float* __restrict__ pb1,
                 const float* __restrict__ P2, const float* __restrict__ pb2,
                 ushort_t* __restrict__ biasb)
{
    const int b  = bid >> 10;
    const int qt = (bid >> 4) & 63;
    const int kt = bid & 15;
    const int tid = threadIdx.x;

    if (tid < 32) {
        S.P[tid][0] = P1[tid];
        S.P[tid][1] = P1[32 + tid];
        S.P[tid][2] = pb1[tid];
        S.P[tid][3] = 0.f;
    }
    for (int e = tid; e < 384; e += 256) S.P[e / 12][4 + e % 12] = P2[e];
    if (tid < 12) S.pb2l[tid] = pb2[tid];
    if (tid < 16) { S.qxl[tid] = sx[b * kL + qt * 16 + tid];
                    S.qyl[tid] = sy[b * kL + qt * 16 + tid]; }
    if (tid < 64) { S.kxl[tid] = sx[b * kL + kt * 64 + tid];
                    S.kyl[tid] = sy[b * kL + kt * 64 + tid]; }
    __syncthreads();

    const int q   = tid >> 4;         // q row 0..15
    const int fq2 = (tid >> 2) & 3;   // k-granule high (reader's fq)
    const int nn  = tid & 3;          // 16-key block
    const float xi = S.qxl[q], yi = S.qyl[q];

    float rx[4], ry[4];
    #pragma unroll
    for (int r = 0; r < 4; ++r) {
        const int kk = nn * 16 + fq2 * 4 + r;
        rx[r] = fminf(fmaxf(xi - S.kxl[kk], -1000.f), 1000.f) * 1e-3f;
        ry[r] = fminf(fmaxf(yi - S.kyl[kk], -1000.f), 1000.f) * 1e-3f;
    }

    float acc[4][12] = {};
    #pragma unroll 4
    for (int u = 0; u < 32; ++u) {
        const float4 pc = *(const float4*)&S.P[u][0];
        const float4 w0 = *(const float4*)&S.P[u][4];
        const float4 w1 = *(const float4*)&S.P[u][8];
        const float4 w2 = *(const float4*)&S.P[u][12];
        float t[4];
        #pragma unroll
        for (int r = 0; r < 4; ++r)
            t[r] = fmaxf(fmaf(rx[r], pc.x, fmaf(ry[r], pc.y, pc.z)), 0.f);
        #pragma unroll
        for (int r = 0; r < 4; ++r) {
            acc[r][0]  = fmaf(t[r], w0.x, acc[r][0]);
            acc[r][1]  = fmaf(t[r], w0.y, acc[r][1]);
            acc[r][2]  = fmaf(t[r], w0.z, acc[r][2]);
            acc[r][3]  = fmaf(t[r], w0.w, acc[r][3]);
            acc[r][4]  = fmaf(t[r], w1.x, acc[r][4]);
            acc[r][5]  = fmaf(t[r], w1.y, acc[r][5]);
            acc[r][6]  = fmaf(t[r], w1.z, acc[r][6]);
            acc[r][7]  = fmaf(t[r], w1.w, acc[r][7]);
            acc[r][8]  = fmaf(t[r], w2.x, acc[r][8]);
            acc[r][9]  = fmaf(t[r], w2.y, acc[r][9]);
            acc[r][10] = fmaf(t[r], w2.z, acc[r][10]);
            acc[r][11] = fmaf(t[r], w2.w, acc[r][11]);
        }
    }

    ushort_t* wbase = &S.Btile[fq2 * 256 + q * 16 + nn * 4];
    #pragma unroll
    for (int h = 0; h < 12; ++h) {
        const float pb = S.pb2l[h] - 4.0f;    // fixed softmax shift folded in
        ushort4 o;
        o.x = f2bf(acc[0][h] + pb);
        o.y = f2bf(acc[1][h] + pb);
        o.z = f2bf(acc[2][h] + pb);
        o.w = f2bf(acc[3][h] + pb);
        *(ushort4*)(wbase + h * 1024) = o;
    }
    __syncthreads();

    #pragma unroll
    for (int i = 0; i < 6; ++i) {
        const int off = (i * 256 + tid) * 8;
        const int h = off >> 10;
        const int inner = off & 1023;
        ushort_t* dst = biasb +
            (((size_t)(b * kNH + h) * 64 + qt) * 16 + kt) * 1024 + inner;
        *(uint4*)dst = *(const uint4*)&S.Btile[off];
    }
}

// ---------------------------------------------------------------------------
// Fused QKV GEMM (blocks 0..287) + bias table (blocks 288..2335).
// V projection writes directly transposed+key-permuted to vt (OUTMODE=2).
// ---------------------------------------------------------------------------
constexpr size_t kQkvSmem =
    sizeof(BiasSmem) > 34816 ? sizeof(BiasSmem) : 34816;

__global__ __launch_bounds__(256)
void qkv_bias_kernel(const ushort_t* __restrict__ A,
                     const ushort_t* wq, const ushort_t* wk, const ushort_t* wv,
                     const float* bq, const float* bk, const float* bv,
                     ushort_t* q, ushort_t* k, ushort_t* vt,
                     const float* __restrict__ sx, const float* __restrict__ sy,
                     const float* __restrict__ P1, const float* __restrict__ pb1,
                     const float* __restrict__ P2, const float* __restrict__ pb2,
                     ushort_t* __restrict__ biasb)
{
    __shared__ __align__(16) char smem[kQkvSmem];
    const int bid = blockIdx.x;

    if (bid < 288) {
        const int z = bid / 96, rem = bid - z * 96;
        const int bx = rem % 6, by = rem / 6;
        if (z == 0)
            gemm_body<0, 1, 1>(A, wq, bq, q,  kD, kD,
                               by * 128, bx * 128, 0, kD, (ushort_t*)smem);
        else if (z == 1)
            gemm_body<0, 1, 1>(A, wk, bk, k,  kD, kD,
                               by * 128, bx * 128, 0, kD, (ushort_t*)smem);
        else
            gemm_body<0, 2, 1>(A, wv, bv, vt, kD, kD,
                               by * 128, bx * 128, 0, kD, (ushort_t*)smem);
    } else {
        bias_body(bid - 288, *(BiasSmem*)smem, sx, sy, P1, pb1, P2, pb2, biasb);
    }
}

// ---------------------------------------------------------------------------
// Pure attention kernel (1536 blocks).  ROUND-10: weight-transpose blocks
// moved to prep — they were this dispatch's real tail (see prep comment).
// Block = (b,h) x 16-q-row tile; 4 waves = 4 K-quarters; 4-way in-block
// combine.  Swapped QK^T + lane-local softmax + permuted-V (r7/r8).
// Bijective XCD swizzle (1536 = 8*192).  No forced occupancy bound (r4).
// ---------------------------------------------------------------------------
__global__ __launch_bounds__(256)
void attn_kernel(const ushort_t* __restrict__ qg, const ushort_t* __restrict__ kg,
                 const ushort_t* __restrict__ vt, const ushort_t* __restrict__ biasb,
                 ushort_t* __restrict__ og)
{
    __shared__ __align__(16) AttnSmem S;
    const int bid = blockIdx.x;
    const int tid = threadIdx.x;

    const int swz  = (bid & 7) * 192 + (bid >> 3);
    const int bh   = swz >> 6;        // 0..23
    const int qt   = swz & 63;        // 16-row q tile index
    const int b  = bh / kNH, h = bh - b * kNH;
    const int z  = tid >> 6;          // wave = K quarter
    const int lane = tid & 63;
    const int fl = lane & 15, fq = lane >> 4;
    const int q0 = qt * 16;
    const int kbeg = z * 256;

    const size_t qoff = (size_t)(b * kL + q0 + fl) * kD + h * kDK + fq * 8;
    const bf16x8 aq0 = *(const bf16x8*)(qg + qoff);
    const bf16x8 aq1 = *(const bf16x8*)(qg + qoff + 32);

    const ushort_t* kbase = kg + (size_t)(b * kL) * kD + h * kDK + fq * 8;
    const ushort_t* vbase = vt + (size_t)(bh * 64) * kL + fq * 8;
    const ushort_t* btile = biasb +
        ((size_t)(bh * 64 + qt) * 16 + z * 4) * 1024 + lane * 16;

    f32x4 accO[4] = {};
    float l_loc = 0.f;                // lane-local l for q = q0+fl

    bf16x8 kc[4][2];
    uint4 bc0, bc1;
    {
        #pragma unroll
        for (int n = 0; n < 4; ++n) {
            const ushort_t* kr = kbase + (size_t)(kbeg + n * 16 + fl) * kD;
            kc[n][0] = *(const bf16x8*)kr;
            kc[n][1] = *(const bf16x8*)(kr + 32);
        }
        bc0 = *(const uint4*)btile;
        bc1 = *(const uint4*)(btile + 8);
    }

    #pragma unroll
    for (int t = 0; t < 4; ++t) {
        const int k0 = kbeg + t * 64;

        bf16x8 vv[4][2];
        #pragma unroll
        for (int n = 0; n < 4; ++n) {
            const ushort_t* vr = vbase + (size_t)(n * 16 + fl) * kL + k0;
            vv[n][0] = *(const bf16x8*)vr;
            vv[n][1] = *(const bf16x8*)(vr + 32);
        }

        // swapped QK^T: S^T[k][q] — A=K, B=Q
        f32x4 Sv[4] = {};
        __builtin_amdgcn_s_setprio(1);
        #pragma unroll
        for (int n = 0; n < 4; ++n) {
            Sv[n] = __builtin_amdgcn_mfma_f32_16x16x32_bf16(kc[n][0], aq0, Sv[n], 0, 0, 0);
            Sv[n] = __builtin_amdgcn_mfma_f32_16x16x32_bf16(kc[n][1], aq1, Sv[n], 0, 0, 0);
        }
        __builtin_amdgcn_s_setprio(0);

        bf16x8 kn[4][2];
        uint4 bn0, bn1;
        if (t < 3) {
            #pragma unroll
            for (int n = 0; n < 4; ++n) {
                const ushort_t* kr = kbase + (size_t)(k0 + 64 + n * 16 + fl) * kD;
                kn[n][0] = *(const bf16x8*)kr;
                kn[n][1] = *(const bf16x8*)(kr + 32);
            }
            bn0 = *(const uint4*)(btile + (t + 1) * 1024);
            bn1 = *(const uint4*)(btile + (t + 1) * 1024 + 8);
        }

        ushort_t bu[16];
        *(uint4*)&bu[0] = bc0;
        *(uint4*)&bu[8] = bc1;

        // lane-local softmax + lane-local P fragments (virtual-k ordering
        // matches vt's folded permutation)
        bf16x8 ap0, ap1;
        #pragma unroll
        for (int n = 0; n < 4; ++n)
            #pragma unroll
            for (int r = 0; r < 4; ++r) {
                const float e = __expf(fmaf(Sv[n][r], 0.125f, bf2f(bu[n * 4 + r])));
                l_loc += e;
                const short pb = (short)f2bf(e);
                if (n < 2) ap0[n * 4 + r] = pb;
                else       ap1[(n - 2) * 4 + r] = pb;
            }

        __builtin_amdgcn_s_setprio(1);
        #pragma unroll
        for (int n = 0; n < 4; ++n) {
            accO[n] = __builtin_amdgcn_mfma_f32_16x16x32_bf16(ap0, vv[n][0], accO[n], 0, 0, 0);
            accO[n] = __builtin_amdgcn_mfma_f32_16x16x32_bf16(ap1, vv[n][1], accO[n], 0, 0, 0);
        }
        __builtin_amdgcn_s_setprio(0);

        if (t < 3) {
            #pragma unroll
            for (int n = 0; n < 4; ++n) { kc[n][0] = kn[n][0]; kc[n][1] = kn[n][1]; }
            bc0 = bn0; bc1 = bn1;
        }
    }

    // full l for q=fl within this wave's K quarter: reduce across fq groups
    float l = l_loc;
    l += __shfl_xor(l, 16, 64);
    l += __shfl_xor(l, 32, 64);

    // inv for output rows q = fq*4+r (held by lane fq*4+r after reduction)
    float inv[4];
    #pragma unroll
    for (int r = 0; r < 4; ++r)
        inv[r] = 1.0f / __shfl(l, fq * 4 + r, 64);

    #pragma unroll
    for (int n = 0; n < 4; ++n)
        #pragma unroll
        for (int r = 0; r < 4; ++r)
            S.Ob[z][fq * 4 + r][n * 16 + fl] = f2bf(accO[n][r] * inv[r]);
    if (lane < 16) S.Ll[z][lane] = l;
    __syncthreads();

    if (tid < 128) {
        const int ri = tid >> 3;            // 0..15 (q row)
        const int d0 = (tid & 7) * 8;       // 8 cols each
        const float w0 = S.Ll[0][ri], w1 = S.Ll[1][ri];
        const float w2 = S.Ll[2][ri], w3 = S.Ll[3][ri];
        const float winv = 1.0f / (w0 + w1 + w2 + w3);
        const float c0 = w0 * winv, c1 = w1 * winv;
        const float c2 = w2 * winv, c3 = w3 * winv;

        ushort_t o[8];
        #pragma unroll
        for (int j = 0; j < 8; ++j)
            o[j] = f2bf(fmaf(c0, bf2f(S.Ob[0][ri][d0 + j]),
                        fmaf(c1, bf2f(S.Ob[1][ri][d0 + j]),
                        fmaf(c2, bf2f(S.Ob[2][ri][d0 + j]),
                             c3 * bf2f(S.Ob[3][ri][d0 + j])))));
        ushort_t* dp = og + (size_t)(b * kL + q0 + ri) * kD + h * kDK + d0;
        *(uint4*)dp = *(const uint4*)o;
    }
}

// ---------------------------------------------------------------------------
// Residual + split-K reduce + bias + LayerNorm.
// ---------------------------------------------------------------------------
template<int NPART, int DUAL>
__global__ __launch_bounds__(256)
void ln_kernel(const float* __restrict__ a, const float* __restrict__ parts,
               const float* __restrict__ bias,
               const float* __restrict__ g, const float* __restrict__ be,
               float* __restrict__ out, ushort_t* __restrict__ out_bf)
{
    const int row = blockIdx.x;
    const int tid = threadIdx.x;
    const float* pa = a + (size_t)row * kD;
    constexpr size_t NTOK = (size_t)kRows * kD;

    float v[3];
    float s = 0.f, sq = 0.f;
    #pragma unroll
    for (int i = 0; i < 3; ++i) {
        const int d = tid + i * 256;
        float t = pa[d] + bias[d];
        #pragma unroll
        for (int p = 0; p < NPART; ++p)
            t += parts[p * NTOK + (size_t)row * kD + d];
        v[i] = t;
        s  += t;
        sq += t * t;
    }
    #pragma unroll
    for (int off = 32; off > 0; off >>= 1) {
        s  += __shfl_down(s, off);
        sq += __shfl_down(sq, off);
    }
    __shared__ float bs[4], bq2[4];
    if ((tid & 63) == 0) { bs[tid >> 6] = s; bq2[tid >> 6] = sq; }
    __syncthreads();
    const float ts = bs[0] + bs[1] + bs[2] + bs[3];
    const float tq = bq2[0] + bq2[1] + bq2[2] + bq2[3];
    const float invn = 1.0f / (float)kD;
    const float mean = ts * invn;
    const float var  = tq * invn - mean * mean;
    const float rstd = rsqrtf(var + kEPS);

    float* po = out + (size_t)row * kD;
    #pragma unroll
    for (int i = 0; i < 3; ++i) {
        const int d = tid + i * 256;
        const float o = (v[i] - mean) * rstd * g[d] + be[d];
        po[d] = o;
        if (DUAL) out_bf[(size_t)row * kD + d] = f2bf(o);
    }
}

// ---------------------------------------------------------------------------
extern "C" void kernel_launch(void* const* d_in, const int* in_sizes, int n_in,
                              void* d_out, int out_size, void* d_ws, size_t ws_size,
                              hipStream_t stream)
{
    const float* src = (const float*)d_in[0];
    const float* sx  = (const float*)d_in[1];
    const float* sy  = (const float*)d_in[2];
    const float* Wq  = (const float*)d_in[3];  const float* bq  = (const float*)d_in[4];
    const float* Wk  = (const float*)d_in[5];  const float* bk  = (const float*)d_in[6];
    const float* Wv  = (const float*)d_in[7];  const float* bv  = (const float*)d_in[8];
    const float* Wo  = (const float*)d_in[9];  const float* bo  = (const float*)d_in[10];
    const float* P1  = (const float*)d_in[11]; const float* pb1 = (const float*)d_in[12];
    const float* P2  = (const float*)d_in[13]; const float* pb2 = (const float*)d_in[14];
    const float* W1  = (const float*)d_in[15]; const float* b1  = (const float*)d_in[16];
    const float* W2  = (const float*)d_in[17]; const float* b2  = (const float*)d_in[18];
    const float* g1  = (const float*)d_in[19]; const float* be1 = (const float*)d_in[20];
    const float* g2  = (const float*)d_in[21]; const float* be2 = (const float*)d_in[22];

    // ---- workspace arena (ushort units) ----
    constexpr size_t W768  = 768u * 768u;
    constexpr size_t W3072 = 768u * 3072u;
    constexpr size_t NTOK  = (size_t)kRows * kD;

    ushort_t* wsu = (ushort_t*)d_ws;
    ushort_t* wqT = wsu;
    ushort_t* wkT = wqT + W768;
    ushort_t* wvT = wkT + W768;
    ushort_t* qb  = wvT + W768;          // Q; dead after attn -> xbf
    ushort_t* kb  = qb + NTOK;
    ushort_t* vb  = kb + NTOK;           // (slot unused; V goes direct to vtb)
    ushort_t* sb  = vb + NTOK;           // src_bf -> attn out
    ushort_t* vtb = sb + NTOK;
    ushort_t* biasb = vtb + NTOK;        // 50 MB bias; dead after attn
    float*    xb    = (float*)(biasb + W768 + 2 * W3072);
    ushort_t* h1bf  = (ushort_t*)(xb + NTOK);
    ushort_t* xbf   = qb;

    const size_t h1off   = (size_t)(h1bf - wsu);
    const size_t bigNeed = (h1off + 20 * NTOK + W768 + 2 * W3072) * 2;
    const bool   big     = ws_size >= bigNeed;

    float*    s2p;
    float*    ff2p;
    ushort_t* scratch;
    int npWo, npFF;
    if (big) {
        s2p     = (float*)h1bf;
        ff2p    = (float*)(h1bf + 8 * NTOK);
        scratch = h1bf + 20 * NTOK;
        npWo = 4; npFF = 6;
    } else {
        s2p     = (float*)h1bf;
        ff2p    = (float*)(h1bf + 4 * NTOK);
        scratch = (ushort_t*)(ff2p + 3 * NTOK);
        npWo = 2; npFF = 3;
    }
    ushort_t* woT2 = scratch;
    ushort_t* w1T2 = woT2 + W768;
    ushort_t* w2T2 = w1T2 + W3072;

    const dim3 blk(256);

    // 1. ALL weight transposes + src->bf16 (fused; wt has no dependencies)
    prep_kernel<<<dim3(3264), blk, 0, stream>>>(
        Wq, Wk, Wv, wqT, wkT, wvT, src, sb, Wo, W1, W2, woT2, w1T2, w2T2);

    // 2. QKV projection (V written transposed+permuted) + bias table (fused)
    qkv_bias_kernel<<<dim3(2336), blk, 0, stream>>>(
        sb, wqT, wkT, wvT, bq, bk, bv, qb, kb, vtb,
        sx, sy, P1, pb1, P2, pb2, biasb);

    // 3. pure attention (1536 blocks = 24 bh x 64 q-tiles, 4-way K-split)
    attn_kernel<<<dim3(1536), blk, 0, stream>>>(qb, kb, vtb, biasb, sb);

    // 4. out-projection, split-K -> fp32 partials
    gemm_splitk_kernel<<<dim3(kD / 128, kRows / 128, npWo), blk, 0, stream>>>(
        sb, woT2, s2p, kD, kD, kD / npWo);

    // 5. LN1: x = LN(src + bo + partials), fp32 + bf16
    if (big) ln_kernel<4, 1><<<dim3(kRows), blk, 0, stream>>>(src, s2p, bo, g1, be1, xb, xbf);
    else     ln_kernel<2, 1><<<dim3(kRows), blk, 0, stream>>>(src, s2p, bo, g1, be1, xb, xbf);

    // 6. FFN1: relu(x @ W1 + b1) -> bf16
    gemm_kernel<1, 1><<<dim3(kFF / 128, kRows / 128), blk, 0, stream>>>(
        xbf, w1T2, b1, h1bf, kFF, kD);

    // 7. FFN2, split-K -> fp32 partials
    gemm_splitk_kernel<<<dim3(kD / 128, kRows / 128, npFF), blk, 0, stream>>>(
        h1bf, w2T2, ff2p, kD, kFF, kFF / npFF);

    // 8. LN2: out = LN(x + b2 + partials)
    if (big) ln_kernel<6, 0><<<dim3(kRows), blk, 0, stream>>>(xb, ff2p, b2, g2, be2,
                                                              (float*)d_out, nullptr);
    else     ln_kernel<3, 0><<<dim3(kRows), blk, 0, stream>>>(xb, ff2p, b2, g2, be2,
                                                              (float*)d_out, nullptr);
}

// Round 11
// 276.365 us; speedup vs baseline: 1.0126x; 1.0126x over previous
//
#include <hip/hip_runtime.h>
#include <math.h>

typedef unsigned short ushort_t;
typedef __attribute__((ext_vector_type(8))) short bf16x8;
typedef __attribute__((ext_vector_type(4))) float f32x4;

constexpr int kD      = 768;
constexpr int kNH     = 12;
constexpr int kDK     = 64;
constexpr int kFF     = 3072;
constexpr int kL      = 1024;
constexpr int kRows   = 2048;     // B * L
constexpr float kEPS  = 1e-5f;

__device__ __forceinline__ ushort_t f2bf(float f) {
    union { float f; unsigned u; } v; v.f = f;
    unsigned r = (v.u + 0x7fffu + ((v.u >> 16) & 1u)) >> 16;
    return (ushort_t)r;
}
__device__ __forceinline__ float bf2f(ushort_t u) {
    union { unsigned u; float f; } v; v.u = ((unsigned)u) << 16; return v.f;
}

#define GL_LDS(gp, lp) __builtin_amdgcn_global_load_lds( \
    (const __attribute__((address_space(1))) void*)(gp), \
    (__attribute__((address_space(3))) void*)(lp), 16, 0, 0)

// ---------------------------------------------------------------------------
// bf16 MFMA GEMM body: 128x128 tile, BK=32, 4 waves, double-buffered LDS.
// Epilogue modes:
//   OUTMODE 0: fp32 direct stores (split-K partials).
//   OUTMODE 1: bf16 via LDS staging -> coalesced uint4 row stores.
//   OUTMODE 2: bf16 transposed via LDS -> V^T tile direct to vt, with the
//              attn-fragment key permutation folded in (see attn kernel).
// LDS supplied by caller: >= 17408 ushorts.  Staging tile [128][136].
// ---------------------------------------------------------------------------
template<int RELU, int OUTMODE, int ADDBIAS>
__device__ __forceinline__ void gemm_body(const ushort_t* __restrict__ A,
                                          const ushort_t* __restrict__ WT,
                                          const float* __restrict__ bias,
                                          void* __restrict__ Cout,
                                          int N, int K, int row0, int col0,
                                          int kbeg, int kend, ushort_t* lds)
{
    const int tid  = threadIdx.x;
    const int lane = tid & 63;
    const int wave = tid >> 6;
    const int wrow = (wave & 1) * 64;
    const int wcol = (wave >> 1) * 64;

    const int srow = wave * 16 + (lane >> 2);
    const int sk   = (lane & 3) * 8;
    const ushort_t* ga0 = A  + (size_t)(row0 + srow)      * K + sk;
    const ushort_t* ga1 = A  + (size_t)(row0 + srow + 64) * K + sk;
    const ushort_t* gb0 = WT + (size_t)(col0 + srow)      * K + sk;
    const ushort_t* gb1 = WT + (size_t)(col0 + srow + 64) * K + sk;

    const int wo = wave * 512;
    const int fl = lane & 15, fq = lane >> 4;

    f32x4 acc[4][4] = {};

    {
        ushort_t* b0 = lds;
        GL_LDS(ga0 + kbeg, b0 + wo);
        GL_LDS(ga1 + kbeg, b0 + 2048 + wo);
        GL_LDS(gb0 + kbeg, b0 + 4096 + wo);
        GL_LDS(gb1 + kbeg, b0 + 4096 + 2048 + wo);
    }
    __syncthreads();

    int cur = 0;
    for (int k0 = kbeg; k0 < kend; k0 += 32) {
        ushort_t* bs = lds + (cur ? 8192 : 0);
        ushort_t* bn = lds + (cur ? 0 : 8192);

        if (k0 + 32 < kend) {
            GL_LDS(ga0 + k0 + 32, bn + wo);
            GL_LDS(ga1 + k0 + 32, bn + 2048 + wo);
            GL_LDS(gb0 + k0 + 32, bn + 4096 + wo);
            GL_LDS(gb1 + k0 + 32, bn + 4096 + 2048 + wo);
        }

        bf16x8 av[4], bv[4];
        #pragma unroll
        for (int i = 0; i < 4; ++i) {
            av[i] = *(const bf16x8*)(bs + (wrow + i * 16 + fl) * 32 + fq * 8);
            bv[i] = *(const bf16x8*)(bs + 4096 + (wcol + i * 16 + fl) * 32 + fq * 8);
        }
        #pragma unroll
        for (int mi = 0; mi < 4; ++mi)
            #pragma unroll
            for (int ni = 0; ni < 4; ++ni)
                acc[mi][ni] = __builtin_amdgcn_mfma_f32_16x16x32_bf16(
                    av[mi], bv[ni], acc[mi][ni], 0, 0, 0);

        __syncthreads();
        cur ^= 1;
    }

    if (OUTMODE == 0) {
        #pragma unroll
        for (int mi = 0; mi < 4; ++mi) {
            const int m = wrow + mi * 16 + fq * 4;
            #pragma unroll
            for (int ni = 0; ni < 4; ++ni) {
                const int n = wcol + ni * 16 + fl;
                const float bb = ADDBIAS ? bias[col0 + n] : 0.f;
                #pragma unroll
                for (int r = 0; r < 4; ++r) {
                    float v = acc[mi][ni][r] + bb;
                    if (RELU) v = fmaxf(v, 0.f);
                    ((float*)Cout)[(size_t)(row0 + m + r) * N + col0 + n] = v;
                }
            }
        }
    } else {
        ushort_t* T = lds;            // [128][136] staging tile
        #pragma unroll
        for (int mi = 0; mi < 4; ++mi) {
            const int m = wrow + mi * 16 + fq * 4;
            #pragma unroll
            for (int ni = 0; ni < 4; ++ni) {
                const int n = wcol + ni * 16 + fl;
                const float bb = ADDBIAS ? bias[col0 + n] : 0.f;
                #pragma unroll
                for (int r = 0; r < 4; ++r) {
                    float v = acc[mi][ni][r] + bb;
                    if (RELU) v = fmaxf(v, 0.f);
                    if (OUTMODE == 1) T[(m + r) * 136 + n] = f2bf(v);
                    else              T[n * 136 + (m + r)] = f2bf(v);
                }
            }
        }
        __syncthreads();
        const int row = tid >> 1;     // token (mode1) / feature (mode2)
        const int seg = tid & 1;      // 64-elem half
        const ushort_t* sp = T + row * 136 + seg * 64;
        if (OUTMODE == 1) {
            ushort_t* dp = (ushort_t*)Cout + (size_t)(row0 + row) * N + col0 + seg * 64;
            #pragma unroll
            for (int i = 0; i < 8; ++i)
                *(uint4*)(dp + i * 8) = *(const uint4*)(sp + i * 8);
        } else {
            const int bb2 = row0 >> 10;            // batch (tiles never straddle)
            const int c   = col0 + row;            // global feature 0..767
            const int vtr = (bb2 * kNH + (c >> 6)) * kDK + (c & 63);
            ushort_t* dp = (ushort_t*)Cout + (size_t)vtr * kL + (row0 & 1023) + seg * 64;
            // permuted gather: output position p (within each 32-token block)
            // holds actual token pi(p); granule (4-token) map pg -> ga:
            //   ga = (pg&1)*4 + (pg>>1)
            uint2 w[16];
            #pragma unroll
            for (int g = 0; g < 16; ++g) {
                const int h32 = g >> 3, pg = g & 7;
                const int srcTok = h32 * 32 + ((pg & 1) * 4 + (pg >> 1)) * 4;
                w[g] = *(const uint2*)(sp + srcTok);
            }
            #pragma unroll
            for (int i = 0; i < 8; ++i) {
                uint4 o; o.x = w[2*i].x; o.y = w[2*i].y;
                o.z = w[2*i+1].x; o.w = w[2*i+1].y;
                *(uint4*)(dp + i * 8) = o;
            }
        }
    }
}

template<int RELU, int OUTMODE>
__global__ __launch_bounds__(256)
void gemm_kernel(const ushort_t* __restrict__ A, const ushort_t* __restrict__ WT,
                 const float* __restrict__ bias, void* __restrict__ Cout,
                 int N, int K)
{
    __shared__ ushort_t lds[17408];
    gemm_body<RELU, OUTMODE, 1>(A, WT, bias, Cout, N, K,
                                blockIdx.y * 128, blockIdx.x * 128, 0, K, lds);
}

__global__ __launch_bounds__(256)
void gemm_splitk_kernel(const ushort_t* __restrict__ A, const ushort_t* __restrict__ WT,
                        float* __restrict__ parts, int N, int K, int kslice)
{
    __shared__ ushort_t lds[17408];
    const int z = blockIdx.z;
    float* out = parts + (size_t)z * kRows * N;
    gemm_body<0, 0, 0>(A, WT, nullptr, out, N, K,
                       blockIdx.y * 128, blockIdx.x * 128,
                       z * kslice, (z + 1) * kslice, lds);
}

// ---------------------------------------------------------------------------
// Weight transpose tile: W[K][N] fp32 -> WT[N][K] bf16, 64x64 tile at (kt,nt).
// ---------------------------------------------------------------------------
__device__ __forceinline__ void wt_tile(const float* __restrict__ src,
                                        ushort_t* __restrict__ dst,
                                        int K, int N, int kt, int nt,
                                        float (*T)[65], int tid)
{
    #pragma unroll
    for (int i = 0; i < 4; ++i) {
        const int e = tid + i * 256;
        const int r = e >> 4;
        const int c = (e & 15) * 4;
        const float4 f = *(const float4*)&src[(size_t)(kt + r) * N + nt + c];
        T[c + 0][r] = f.x; T[c + 1][r] = f.y; T[c + 2][r] = f.z; T[c + 3][r] = f.w;
    }
    __syncthreads();
    #pragma unroll
    for (int i = 0; i < 4; ++i) {
        const int e = tid + i * 256;
        const int n = e >> 4;
        const int kc = (e & 15) * 4;
        ushort4 o;
        o.x = f2bf(T[n][kc + 0]); o.y = f2bf(T[n][kc + 1]);
        o.z = f2bf(T[n][kc + 2]); o.w = f2bf(T[n][kc + 3]);
        *(ushort4*)&dst[(size_t)(nt + n) * K + kt + kc] = o;
    }
}

// ---------------------------------------------------------------------------
// prep: blocks 0..431 = early weight transposes (Wq,Wk,Wv; 144 tiles each);
//       blocks 432..1967 = src fp32->bf16 (1536 blocks).
// ROUND-11: late wt (Wo/W1/W2) moved into the qkv_bias dispatch — in prep
// they SERIALIZED (r10: prep had nothing to hide them under, total +2us);
// qkv_bias is VALU-bound (35% VALU / 17% HBM) so HBM-latency-bound wt
// blocks are its complement.
// ---------------------------------------------------------------------------
__global__ __launch_bounds__(256)
void prep_kernel(const float* __restrict__ Wq, const float* __restrict__ Wk,
                 const float* __restrict__ Wv,
                 ushort_t* wqT, ushort_t* wkT, ushort_t* wvT,
                 const float* __restrict__ src, ushort_t* __restrict__ sb)
{
    __shared__ float T[64][65];
    const int bid = blockIdx.x;
    const int tid = threadIdx.x;

    if (bid < 432) {
        const int wz = bid / 144, t = bid - wz * 144;
        const float* s = (wz == 0) ? Wq : (wz == 1) ? Wk : Wv;
        ushort_t*   d = (wz == 0) ? wqT : (wz == 1) ? wkT : wvT;
        wt_tile(s, d, kD, kD, (t % 12) * 64, (t / 12) * 64, T, tid);
    } else {
        const int i = (bid - 432) * 256 + tid;
        const float4 f = ((const float4*)src)[i];
        ushort4 o;
        o.x = f2bf(f.x); o.y = f2bf(f.y); o.z = f2bf(f.z); o.w = f2bf(f.w);
        ((ushort4*)sb)[i] = o;
    }
}

// ---------------------------------------------------------------------------
// Shared-memory layouts for the fused kernels.
// ---------------------------------------------------------------------------
struct BiasSmem {                 // 27312 B
    float P[32][16];              // [u] = {A,B,C,0, W2[0..11]}
    float pb2l[12];
    float qxl[16], qyl[16], kxl[64], kyl[64];
    ushort_t Btile[12 * 1024];
};
struct AttnSmem {                 // 8960 B (Ob rows padded 64->68:
    ushort_t Ob[4][16][68];       //  stride 136 B spreads the 4 fq-lanes to
    float    Ll[4][16];           //  banks +0/8/16/24 -> conflict-free,
};                                //  verified r10: SQ_LDS_BANK_CONFLICT = 0)

// ---------------------------------------------------------------------------
// Relative-position bias tile body (-4 shift folded).
// Thread remap (q=tid>>4, fq2=(tid>>2)&3, n=tid&3): 4 outputs land in 4
// CONSECUTIVE Btile slots -> 12 ushort4 stores (bank-balanced).
// Slot layout matches the swapped-QK attention fragment.
// ---------------------------------------------------------------------------
__device__ __forceinline__ void bias_body(int bid, BiasSmem& S,
                 const float* __restrict__ sx, const float* __restrict__ sy,
                 const float* __restrict__ P1, const float* __restrict__ pb1,
                 const float* __restrict__ P2, const float* __restrict__ pb2,
                 ushort_t* __restrict__ biasb)
{
    const int b  = bid >> 10;
    const int qt = (bid >> 4) & 63;
    const int kt = bid & 15;
    const int tid = threadIdx.x;

    if (tid < 32) {
        S.P[tid][0] = P1[tid];
        S.P[tid][1] = P1[32 + tid];
        S.P[tid][2] = pb1[tid];
        S.P[tid][3] = 0.f;
    }
    for (int e = tid; e < 384; e += 256) S.P[e / 12][4 + e % 12] = P2[e];
    if (tid < 12) S.pb2l[tid] = pb2[tid];
    if (tid < 16) { S.qxl[tid] = sx[b * kL + qt * 16 + tid];
                    S.qyl[tid] = sy[b * kL + qt * 16 + tid]; }
    if (tid < 64) { S.kxl[tid] = sx[b * kL + kt * 64 + tid];
                    S.kyl[tid] = sy[b * kL + kt * 64 + tid]; }
    __syncthreads();

    const int q   = tid >> 4;         // q row 0..15
    const int fq2 = (tid >> 2) & 3;   // k-granule high (reader's fq)
    const int nn  = tid & 3;          // 16-key block
    const float xi = S.qxl[q], yi = S.qyl[q];

    float rx[4], ry[4];
    #pragma unroll
    for (int r = 0; r < 4; ++r) {
        const int kk = nn * 16 + fq2 * 4 + r;
        rx[r] = fminf(fmaxf(xi - S.kxl[kk], -1000.f), 1000.f) * 1e-3f;
        ry[r] = fminf(fmaxf(yi - S.kyl[kk], -1000.f), 1000.f) * 1e-3f;
    }

    float acc[4][12] = {};
    #pragma unroll 4
    for (int u = 0; u < 32; ++u) {
        const float4 pc = *(const float4*)&S.P[u][0];
        const float4 w0 = *(const float4*)&S.P[u][4];
        const float4 w1 = *(const float4*)&S.P[u][8];
        const float4 w2 = *(const float4*)&S.P[u][12];
        float t[4];
        #pragma unroll
        for (int r = 0; r < 4; ++r)
            t[r] = fmaxf(fmaf(rx[r], pc.x, fmaf(ry[r], pc.y, pc.z)), 0.f);
        #pragma unroll
        for (int r = 0; r < 4; ++r) {
            acc[r][0]  = fmaf(t[r], w0.x, acc[r][0]);
            acc[r][1]  = fmaf(t[r], w0.y, acc[r][1]);
            acc[r][2]  = fmaf(t[r], w0.z, acc[r][2]);
            acc[r][3]  = fmaf(t[r], w0.w, acc[r][3]);
            acc[r][4]  = fmaf(t[r], w1.x, acc[r][4]);
            acc[r][5]  = fmaf(t[r], w1.y, acc[r][5]);
            acc[r][6]  = fmaf(t[r], w1.z, acc[r][6]);
            acc[r][7]  = fmaf(t[r], w1.w, acc[r][7]);
            acc[r][8]  = fmaf(t[r], w2.x, acc[r][8]);
            acc[r][9]  = fmaf(t[r], w2.y, acc[r][9]);
            acc[r][10] = fmaf(t[r], w2.z, acc[r][10]);
            acc[r][11] = fmaf(t[r], w2.w, acc[r][11]);
        }
    }

    ushort_t* wbase = &S.Btile[fq2 * 256 + q * 16 + nn * 4];
    #pragma unroll
    for (int h = 0; h < 12; ++h) {
        const float pb = S.pb2l[h] - 4.0f;    // fixed softmax shift folded in
        ushort4 o;
        o.x = f2bf(acc[0][h] + pb);
        o.y = f2bf(acc[1][h] + pb);
        o.z = f2bf(acc[2][h] + pb);
        o.w = f2bf(acc[3][h] + pb);
        *(ushort4*)(wbase + h * 1024) = o;
    }
    __syncthreads();

    #pragma unroll
    for (int i = 0; i < 6; ++i) {
        const int off = (i * 256 + tid) * 8;
        const int h = off >> 10;
        const int inner = off & 1023;
        ushort_t* dst = biasb +
            (((size_t)(b * kNH + h) * 64 + qt) * 16 + kt) * 1024 + inner;
        *(uint4*)dst = *(const uint4*)&S.Btile[off];
    }
}

// ---------------------------------------------------------------------------
// Fused QKV GEMM (0..287) + bias table (288..2335) + late weight transposes
// (2336..3631).  ROUND-11: wt blocks co-dispatched HERE — this dispatch is
// VALU-bound, wt is HBM-latency-bound (complementary resources), and wt's
// consumers are dispatches 4+ so ordering is legal.  V projection writes
// directly transposed+key-permuted to vt (OUTMODE=2).
// ---------------------------------------------------------------------------
constexpr size_t kQkvSmem =
    sizeof(BiasSmem) > 34816 ? sizeof(BiasSmem) : 34816;

__global__ __launch_bounds__(256)
void qkv_bias_kernel(const ushort_t* __restrict__ A,
                     const ushort_t* wq, const ushort_t* wk, const ushort_t* wv,
                     const float* bq, const float* bk, const float* bv,
                     ushort_t* q, ushort_t* k, ushort_t* vt,
                     const float* __restrict__ sx, const float* __restrict__ sy,
                     const float* __restrict__ P1, const float* __restrict__ pb1,
                     const float* __restrict__ P2, const float* __restrict__ pb2,
                     ushort_t* __restrict__ biasb,
                     const float* __restrict__ Wo, const float* __restrict__ W1,
                     const float* __restrict__ W2,
                     ushort_t* woT, ushort_t* w1T, ushort_t* w2T)
{
    __shared__ __align__(16) char smem[kQkvSmem];
    const int bid = blockIdx.x;

    if (bid < 288) {
        const int z = bid / 96, rem = bid - z * 96;
        const int bx = rem % 6, by = rem / 6;
        if (z == 0)
            gemm_body<0, 1, 1>(A, wq, bq, q,  kD, kD,
                               by * 128, bx * 128, 0, kD, (ushort_t*)smem);
        else if (z == 1)
            gemm_body<0, 1, 1>(A, wk, bk, k,  kD, kD,
                               by * 128, bx * 128, 0, kD, (ushort_t*)smem);
        else
            gemm_body<0, 2, 1>(A, wv, bv, vt, kD, kD,
                               by * 128, bx * 128, 0, kD, (ushort_t*)smem);
    } else if (bid < 2336) {
        bias_body(bid - 288, *(BiasSmem*)smem, sx, sy, P1, pb1, P2, pb2, biasb);
    } else {
        float (*T)[65] = (float(*)[65])smem;
        const int t = bid - 2336;
        if (t < 144)      wt_tile(Wo, woT, kD,  kD,  (t % 12) * 64, (t / 12) * 64, T, threadIdx.x);
        else if (t < 720) { const int t2 = t - 144;
                            wt_tile(W1, w1T, kD,  kFF, (t2 % 12) * 64, (t2 / 12) * 64, T, threadIdx.x); }
        else              { const int t2 = t - 720;
                            wt_tile(W2, w2T, kFF, kD,  (t2 % 48) * 64, (t2 / 48) * 64, T, threadIdx.x); }
    }
}

// ---------------------------------------------------------------------------
// Pure attention kernel (1536 blocks) — r10 verified at 50.2 us, 0 LDS
// conflicts.  Block = (b,h) x 16-q-row tile; 4 waves = 4 K-quarters; 4-way
// in-block combine.  Swapped QK^T + lane-local softmax + permuted-V.
// Bijective XCD swizzle (1536 = 8*192).  No forced occupancy bound (r4).
// ---------------------------------------------------------------------------
__global__ __launch_bounds__(256)
void attn_kernel(const ushort_t* __restrict__ qg, const ushort_t* __restrict__ kg,
                 const ushort_t* __restrict__ vt, const ushort_t* __restrict__ biasb,
                 ushort_t* __restrict__ og)
{
    __shared__ __align__(16) AttnSmem S;
    const int bid = blockIdx.x;
    const int tid = threadIdx.x;

    const int swz  = (bid & 7) * 192 + (bid >> 3);
    const int bh   = swz >> 6;        // 0..23
    const int qt   = swz & 63;        // 16-row q tile index
    const int b  = bh / kNH, h = bh - b * kNH;
    const int z  = tid >> 6;          // wave = K quarter
    const int lane = tid & 63;
    const int fl = lane & 15, fq = lane >> 4;
    const int q0 = qt * 16;
    const int kbeg = z * 256;

    const size_t qoff = (size_t)(b * kL + q0 + fl) * kD + h * kDK + fq * 8;
    const bf16x8 aq0 = *(const bf16x8*)(qg + qoff);
    const bf16x8 aq1 = *(const bf16x8*)(qg + qoff + 32);

    const ushort_t* kbase = kg + (size_t)(b * kL) * kD + h * kDK + fq * 8;
    const ushort_t* vbase = vt + (size_t)(bh * 64) * kL + fq * 8;
    const ushort_t* btile = biasb +
        ((size_t)(bh * 64 + qt) * 16 + z * 4) * 1024 + lane * 16;

    f32x4 accO[4] = {};
    float l_loc = 0.f;                // lane-local l for q = q0+fl

    bf16x8 kc[4][2];
    uint4 bc0, bc1;
    {
        #pragma unroll
        for (int n = 0; n < 4; ++n) {
            const ushort_t* kr = kbase + (size_t)(kbeg + n * 16 + fl) * kD;
            kc[n][0] = *(const bf16x8*)kr;
            kc[n][1] = *(const bf16x8*)(kr + 32);
        }
        bc0 = *(const uint4*)btile;
        bc1 = *(const uint4*)(btile + 8);
    }

    #pragma unroll
    for (int t = 0; t < 4; ++t) {
        const int k0 = kbeg + t * 64;

        bf16x8 vv[4][2];
        #pragma unroll
        for (int n = 0; n < 4; ++n) {
            const ushort_t* vr = vbase + (size_t)(n * 16 + fl) * kL + k0;
            vv[n][0] = *(const bf16x8*)vr;
            vv[n][1] = *(const bf16x8*)(vr + 32);
        }

        // swapped QK^T: S^T[k][q] — A=K, B=Q
        f32x4 Sv[4] = {};
        __builtin_amdgcn_s_setprio(1);
        #pragma unroll
        for (int n = 0; n < 4; ++n) {
            Sv[n] = __builtin_amdgcn_mfma_f32_16x16x32_bf16(kc[n][0], aq0, Sv[n], 0, 0, 0);
            Sv[n] = __builtin_amdgcn_mfma_f32_16x16x32_bf16(kc[n][1], aq1, Sv[n], 0, 0, 0);
        }
        __builtin_amdgcn_s_setprio(0);

        bf16x8 kn[4][2];
        uint4 bn0, bn1;
        if (t < 3) {
            #pragma unroll
            for (int n = 0; n < 4; ++n) {
                const ushort_t* kr = kbase + (size_t)(k0 + 64 + n * 16 + fl) * kD;
                kn[n][0] = *(const bf16x8*)kr;
                kn[n][1] = *(const bf16x8*)(kr + 32);
            }
            bn0 = *(const uint4*)(btile + (t + 1) * 1024);
            bn1 = *(const uint4*)(btile + (t + 1) * 1024 + 8);
        }

        ushort_t bu[16];
        *(uint4*)&bu[0] = bc0;
        *(uint4*)&bu[8] = bc1;

        // lane-local softmax + lane-local P fragments (virtual-k ordering
        // matches vt's folded permutation)
        bf16x8 ap0, ap1;
        #pragma unroll
        for (int n = 0; n < 4; ++n)
            #pragma unroll
            for (int r = 0; r < 4; ++r) {
                const float e = __expf(fmaf(Sv[n][r], 0.125f, bf2f(bu[n * 4 + r])));
                l_loc += e;
                const short pb = (short)f2bf(e);
                if (n < 2) ap0[n * 4 + r] = pb;
                else       ap1[(n - 2) * 4 + r] = pb;
            }

        __builtin_amdgcn_s_setprio(1);
        #pragma unroll
        for (int n = 0; n < 4; ++n) {
            accO[n] = __builtin_amdgcn_mfma_f32_16x16x32_bf16(ap0, vv[n][0], accO[n], 0, 0, 0);
            accO[n] = __builtin_amdgcn_mfma_f32_16x16x32_bf16(ap1, vv[n][1], accO[n], 0, 0, 0);
        }
        __builtin_amdgcn_s_setprio(0);

        if (t < 3) {
            #pragma unroll
            for (int n = 0; n < 4; ++n) { kc[n][0] = kn[n][0]; kc[n][1] = kn[n][1]; }
            bc0 = bn0; bc1 = bn1;
        }
    }

    // full l for q=fl within this wave's K quarter: reduce across fq groups
    float l = l_loc;
    l += __shfl_xor(l, 16, 64);
    l += __shfl_xor(l, 32, 64);

    // inv for output rows q = fq*4+r (held by lane fq*4+r after reduction)
    float inv[4];
    #pragma unroll
    for (int r = 0; r < 4; ++r)
        inv[r] = 1.0f / __shfl(l, fq * 4 + r, 64);

    #pragma unroll
    for (int n = 0; n < 4; ++n)
        #pragma unroll
        for (int r = 0; r < 4; ++r)
            S.Ob[z][fq * 4 + r][n * 16 + fl] = f2bf(accO[n][r] * inv[r]);
    if (lane < 16) S.Ll[z][lane] = l;
    __syncthreads();

    if (tid < 128) {
        const int ri = tid >> 3;            // 0..15 (q row)
        const int d0 = (tid & 7) * 8;       // 8 cols each
        const float w0 = S.Ll[0][ri], w1 = S.Ll[1][ri];
        const float w2 = S.Ll[2][ri], w3 = S.Ll[3][ri];
        const float winv = 1.0f / (w0 + w1 + w2 + w3);
        const float c0 = w0 * winv, c1 = w1 * winv;
        const float c2 = w2 * winv, c3 = w3 * winv;

        ushort_t o[8];
        #pragma unroll
        for (int j = 0; j < 8; ++j)
            o[j] = f2bf(fmaf(c0, bf2f(S.Ob[0][ri][d0 + j]),
                        fmaf(c1, bf2f(S.Ob[1][ri][d0 + j]),
                        fmaf(c2, bf2f(S.Ob[2][ri][d0 + j]),
                             c3 * bf2f(S.Ob[3][ri][d0 + j])))));
        ushort_t* dp = og + (size_t)(b * kL + q0 + ri) * kD + h * kDK + d0;
        *(uint4*)dp = *(const uint4*)o;
    }
}

// ---------------------------------------------------------------------------
// Residual + split-K reduce + bias + LayerNorm.
// ---------------------------------------------------------------------------
template<int NPART, int DUAL>
__global__ __launch_bounds__(256)
void ln_kernel(const float* __restrict__ a, const float* __restrict__ parts,
               const float* __restrict__ bias,
               const float* __restrict__ g, const float* __restrict__ be,
               float* __restrict__ out, ushort_t* __restrict__ out_bf)
{
    const int row = blockIdx.x;
    const int tid = threadIdx.x;
    const float* pa = a + (size_t)row * kD;
    constexpr size_t NTOK = (size_t)kRows * kD;

    float v[3];
    float s = 0.f, sq = 0.f;
    #pragma unroll
    for (int i = 0; i < 3; ++i) {
        const int d = tid + i * 256;
        float t = pa[d] + bias[d];
        #pragma unroll
        for (int p = 0; p < NPART; ++p)
            t += parts[p * NTOK + (size_t)row * kD + d];
        v[i] = t;
        s  += t;
        sq += t * t;
    }
    #pragma unroll
    for (int off = 32; off > 0; off >>= 1) {
        s  += __shfl_down(s, off);
        sq += __shfl_down(sq, off);
    }
    __shared__ float bs[4], bq2[4];
    if ((tid & 63) == 0) { bs[tid >> 6] = s; bq2[tid >> 6] = sq; }
    __syncthreads();
    const float ts = bs[0] + bs[1] + bs[2] + bs[3];
    const float tq = bq2[0] + bq2[1] + bq2[2] + bq2[3];
    const float invn = 1.0f / (float)kD;
    const float mean = ts * invn;
    const float var  = tq * invn - mean * mean;
    const float rstd = rsqrtf(var + kEPS);

    float* po = out + (size_t)row * kD;
    #pragma unroll
    for (int i = 0; i < 3; ++i) {
        const int d = tid + i * 256;
        const float o = (v[i] - mean) * rstd * g[d] + be[d];
        po[d] = o;
        if (DUAL) out_bf[(size_t)row * kD + d] = f2bf(o);
    }
}

// ---------------------------------------------------------------------------
extern "C" void kernel_launch(void* const* d_in, const int* in_sizes, int n_in,
                              void* d_out, int out_size, void* d_ws, size_t ws_size,
                              hipStream_t stream)
{
    const float* src = (const float*)d_in[0];
    const float* sx  = (const float*)d_in[1];
    const float* sy  = (const float*)d_in[2];
    const float* Wq  = (const float*)d_in[3];  const float* bq  = (const float*)d_in[4];
    const float* Wk  = (const float*)d_in[5];  const float* bk  = (const float*)d_in[6];
    const float* Wv  = (const float*)d_in[7];  const float* bv  = (const float*)d_in[8];
    const float* Wo  = (const float*)d_in[9];  const float* bo  = (const float*)d_in[10];
    const float* P1  = (const float*)d_in[11]; const float* pb1 = (const float*)d_in[12];
    const float* P2  = (const float*)d_in[13]; const float* pb2 = (const float*)d_in[14];
    const float* W1  = (const float*)d_in[15]; const float* b1  = (const float*)d_in[16];
    const float* W2  = (const float*)d_in[17]; const float* b2  = (const float*)d_in[18];
    const float* g1  = (const float*)d_in[19]; const float* be1 = (const float*)d_in[20];
    const float* g2  = (const float*)d_in[21]; const float* be2 = (const float*)d_in[22];

    // ---- workspace arena (ushort units) ----
    constexpr size_t W768  = 768u * 768u;
    constexpr size_t W3072 = 768u * 3072u;
    constexpr size_t NTOK  = (size_t)kRows * kD;

    ushort_t* wsu = (ushort_t*)d_ws;
    ushort_t* wqT = wsu;
    ushort_t* wkT = wqT + W768;
    ushort_t* wvT = wkT + W768;
    ushort_t* qb  = wvT + W768;          // Q; dead after attn -> xbf
    ushort_t* kb  = qb + NTOK;
    ushort_t* vb  = kb + NTOK;           // (slot unused; V goes direct to vtb)
    ushort_t* sb  = vb + NTOK;           // src_bf -> attn out
    ushort_t* vtb = sb + NTOK;
    ushort_t* biasb = vtb + NTOK;        // 50 MB bias; dead after attn
    float*    xb    = (float*)(biasb + W768 + 2 * W3072);
    ushort_t* h1bf  = (ushort_t*)(xb + NTOK);
    ushort_t* xbf   = qb;

    const size_t h1off   = (size_t)(h1bf - wsu);
    const size_t bigNeed = (h1off + 20 * NTOK + W768 + 2 * W3072) * 2;
    const bool   big     = ws_size >= bigNeed;

    float*    s2p;
    float*    ff2p;
    ushort_t* scratch;
    int npWo, npFF;
    if (big) {
        s2p     = (float*)h1bf;
        ff2p    = (float*)(h1bf + 8 * NTOK);
        scratch = h1bf + 20 * NTOK;
        npWo = 4; npFF = 6;
    } else {
        s2p     = (float*)h1bf;
        ff2p    = (float*)(h1bf + 4 * NTOK);
        scratch = (ushort_t*)(ff2p + 3 * NTOK);
        npWo = 2; npFF = 3;
    }
    ushort_t* woT2 = scratch;
    ushort_t* w1T2 = woT2 + W768;
    ushort_t* w2T2 = w1T2 + W3072;

    const dim3 blk(256);

    // 1. early weight transposes + src->bf16 (fused)
    prep_kernel<<<dim3(1968), blk, 0, stream>>>(Wq, Wk, Wv, wqT, wkT, wvT, src, sb);

    // 2. QKV projection + bias table + late weight transposes (co-dispatched:
    //    wt's HBM-latency blocks overlap the VALU-bound bias work)
    qkv_bias_kernel<<<dim3(3632), blk, 0, stream>>>(
        sb, wqT, wkT, wvT, bq, bk, bv, qb, kb, vtb,
        sx, sy, P1, pb1, P2, pb2, biasb, Wo, W1, W2, woT2, w1T2, w2T2);

    // 3. pure attention (1536 blocks = 24 bh x 64 q-tiles, 4-way K-split)
    attn_kernel<<<dim3(1536), blk, 0, stream>>>(qb, kb, vtb, biasb, sb);

    // 4. out-projection, split-K -> fp32 partials
    gemm_splitk_kernel<<<dim3(kD / 128, kRows / 128, npWo), blk, 0, stream>>>(
        sb, woT2, s2p, kD, kD, kD / npWo);

    // 5. LN1: x = LN(src + bo + partials), fp32 + bf16
    if (big) ln_kernel<4, 1><<<dim3(kRows), blk, 0, stream>>>(src, s2p, bo, g1, be1, xb, xbf);
    else     ln_kernel<2, 1><<<dim3(kRows), blk, 0, stream>>>(src, s2p, bo, g1, be1, xb, xbf);

    // 6. FFN1: relu(x @ W1 + b1) -> bf16
    gemm_kernel<1, 1><<<dim3(kFF / 128, kRows / 128), blk, 0, stream>>>(
        xbf, w1T2, b1, h1bf, kFF, kD);

    // 7. FFN2, split-K -> fp32 partials
    gemm_splitk_kernel<<<dim3(kD / 128, kRows / 128, npFF), blk, 0, stream>>>(
        h1bf, w2T2, ff2p, kD, kFF, kFF / npFF);

    // 8. LN2: out = LN(x + b2 + partials)
    if (big) ln_kernel<6, 0><<<dim3(kRows), blk, 0, stream>>>(xb, ff2p, b2, g2, be2,
                                                              (float*)d_out, nullptr);
    else     ln_kernel<3, 0><<<dim3(kRows), blk, 0, stream>>>(xb, ff2p, b2, g2, be2,
                                                              (float*)d_out, nullptr);
}

// Round 12
// 275.263 us; speedup vs baseline: 1.0167x; 1.0040x over previous
//
#include <hip/hip_runtime.h>
#include <math.h>

typedef unsigned short ushort_t;
typedef __attribute__((ext_vector_type(8))) short bf16x8;
typedef __attribute__((ext_vector_type(4))) float f32x4;

constexpr int kD      = 768;
constexpr int kNH     = 12;
constexpr int kDK     = 64;
constexpr int kFF     = 3072;
constexpr int kL      = 1024;
constexpr int kRows   = 2048;     // B * L
constexpr float kEPS  = 1e-5f;

__device__ __forceinline__ ushort_t f2bf(float f) {
    union { float f; unsigned u; } v; v.f = f;
    unsigned r = (v.u + 0x7fffu + ((v.u >> 16) & 1u)) >> 16;
    return (ushort_t)r;
}
__device__ __forceinline__ float bf2f(ushort_t u) {
    union { unsigned u; float f; } v; v.u = ((unsigned)u) << 16; return v.f;
}

#define GL_LDS(gp, lp) __builtin_amdgcn_global_load_lds( \
    (const __attribute__((address_space(1))) void*)(gp), \
    (__attribute__((address_space(3))) void*)(lp), 16, 0, 0)

// ---------------------------------------------------------------------------
// bf16 MFMA GEMM body: 128x128 tile, BK=32, 4 waves, double-buffered LDS.
// Epilogue modes:
//   OUTMODE 0: fp32 direct stores (split-K partials).
//   OUTMODE 1: bf16 via LDS staging -> coalesced uint4 row stores.
//   OUTMODE 2: bf16 transposed via LDS -> V^T tile direct to vt, with the
//              attn-fragment key permutation folded in (see attn kernel).
// LDS supplied by caller: >= 17408 ushorts.  Staging tile [128][136].
// ---------------------------------------------------------------------------
template<int RELU, int OUTMODE, int ADDBIAS>
__device__ __forceinline__ void gemm_body(const ushort_t* __restrict__ A,
                                          const ushort_t* __restrict__ WT,
                                          const float* __restrict__ bias,
                                          void* __restrict__ Cout,
                                          int N, int K, int row0, int col0,
                                          int kbeg, int kend, ushort_t* lds)
{
    const int tid  = threadIdx.x;
    const int lane = tid & 63;
    const int wave = tid >> 6;
    const int wrow = (wave & 1) * 64;
    const int wcol = (wave >> 1) * 64;

    const int srow = wave * 16 + (lane >> 2);
    const int sk   = (lane & 3) * 8;
    const ushort_t* ga0 = A  + (size_t)(row0 + srow)      * K + sk;
    const ushort_t* ga1 = A  + (size_t)(row0 + srow + 64) * K + sk;
    const ushort_t* gb0 = WT + (size_t)(col0 + srow)      * K + sk;
    const ushort_t* gb1 = WT + (size_t)(col0 + srow + 64) * K + sk;

    const int wo = wave * 512;
    const int fl = lane & 15, fq = lane >> 4;

    f32x4 acc[4][4] = {};

    {
        ushort_t* b0 = lds;
        GL_LDS(ga0 + kbeg, b0 + wo);
        GL_LDS(ga1 + kbeg, b0 + 2048 + wo);
        GL_LDS(gb0 + kbeg, b0 + 4096 + wo);
        GL_LDS(gb1 + kbeg, b0 + 4096 + 2048 + wo);
    }
    __syncthreads();

    int cur = 0;
    for (int k0 = kbeg; k0 < kend; k0 += 32) {
        ushort_t* bs = lds + (cur ? 8192 : 0);
        ushort_t* bn = lds + (cur ? 0 : 8192);

        if (k0 + 32 < kend) {
            GL_LDS(ga0 + k0 + 32, bn + wo);
            GL_LDS(ga1 + k0 + 32, bn + 2048 + wo);
            GL_LDS(gb0 + k0 + 32, bn + 4096 + wo);
            GL_LDS(gb1 + k0 + 32, bn + 4096 + 2048 + wo);
        }

        bf16x8 av[4], bv[4];
        #pragma unroll
        for (int i = 0; i < 4; ++i) {
            av[i] = *(const bf16x8*)(bs + (wrow + i * 16 + fl) * 32 + fq * 8);
            bv[i] = *(const bf16x8*)(bs + 4096 + (wcol + i * 16 + fl) * 32 + fq * 8);
        }
        #pragma unroll
        for (int mi = 0; mi < 4; ++mi)
            #pragma unroll
            for (int ni = 0; ni < 4; ++ni)
                acc[mi][ni] = __builtin_amdgcn_mfma_f32_16x16x32_bf16(
                    av[mi], bv[ni], acc[mi][ni], 0, 0, 0);

        __syncthreads();
        cur ^= 1;
    }

    if (OUTMODE == 0) {
        #pragma unroll
        for (int mi = 0; mi < 4; ++mi) {
            const int m = wrow + mi * 16 + fq * 4;
            #pragma unroll
            for (int ni = 0; ni < 4; ++ni) {
                const int n = wcol + ni * 16 + fl;
                const float bb = ADDBIAS ? bias[col0 + n] : 0.f;
                #pragma unroll
                for (int r = 0; r < 4; ++r) {
                    float v = acc[mi][ni][r] + bb;
                    if (RELU) v = fmaxf(v, 0.f);
                    ((float*)Cout)[(size_t)(row0 + m + r) * N + col0 + n] = v;
                }
            }
        }
    } else {
        ushort_t* T = lds;            // [128][136] staging tile
        #pragma unroll
        for (int mi = 0; mi < 4; ++mi) {
            const int m = wrow + mi * 16 + fq * 4;
            #pragma unroll
            for (int ni = 0; ni < 4; ++ni) {
                const int n = wcol + ni * 16 + fl;
                const float bb = ADDBIAS ? bias[col0 + n] : 0.f;
                #pragma unroll
                for (int r = 0; r < 4; ++r) {
                    float v = acc[mi][ni][r] + bb;
                    if (RELU) v = fmaxf(v, 0.f);
                    if (OUTMODE == 1) T[(m + r) * 136 + n] = f2bf(v);
                    else              T[n * 136 + (m + r)] = f2bf(v);
                }
            }
        }
        __syncthreads();
        const int row = tid >> 1;     // token (mode1) / feature (mode2)
        const int seg = tid & 1;      // 64-elem half
        const ushort_t* sp = T + row * 136 + seg * 64;
        if (OUTMODE == 1) {
            ushort_t* dp = (ushort_t*)Cout + (size_t)(row0 + row) * N + col0 + seg * 64;
            #pragma unroll
            for (int i = 0; i < 8; ++i)
                *(uint4*)(dp + i * 8) = *(const uint4*)(sp + i * 8);
        } else {
            const int bb2 = row0 >> 10;            // batch (tiles never straddle)
            const int c   = col0 + row;            // global feature 0..767
            const int vtr = (bb2 * kNH + (c >> 6)) * kDK + (c & 63);
            ushort_t* dp = (ushort_t*)Cout + (size_t)vtr * kL + (row0 & 1023) + seg * 64;
            // permuted gather: output position p (within each 32-token block)
            // holds actual token pi(p); granule (4-token) map pg -> ga:
            //   ga = (pg&1)*4 + (pg>>1)
            uint2 w[16];
            #pragma unroll
            for (int g = 0; g < 16; ++g) {
                const int h32 = g >> 3, pg = g & 7;
                const int srcTok = h32 * 32 + ((pg & 1) * 4 + (pg >> 1)) * 4;
                w[g] = *(const uint2*)(sp + srcTok);
            }
            #pragma unroll
            for (int i = 0; i < 8; ++i) {
                uint4 o; o.x = w[2*i].x; o.y = w[2*i].y;
                o.z = w[2*i+1].x; o.w = w[2*i+1].y;
                *(uint4*)(dp + i * 8) = o;
            }
        }
    }
}

template<int RELU, int OUTMODE>
__global__ __launch_bounds__(256)
void gemm_kernel(const ushort_t* __restrict__ A, const ushort_t* __restrict__ WT,
                 const float* __restrict__ bias, void* __restrict__ Cout,
                 int N, int K)
{
    __shared__ ushort_t lds[17408];
    gemm_body<RELU, OUTMODE, 1>(A, WT, bias, Cout, N, K,
                                blockIdx.y * 128, blockIdx.x * 128, 0, K, lds);
}

__global__ __launch_bounds__(256)
void gemm_splitk_kernel(const ushort_t* __restrict__ A, const ushort_t* __restrict__ WT,
                        float* __restrict__ parts, int N, int K, int kslice)
{
    __shared__ ushort_t lds[17408];
    const int z = blockIdx.z;
    float* out = parts + (size_t)z * kRows * N;
    gemm_body<0, 0, 0>(A, WT, nullptr, out, N, K,
                       blockIdx.y * 128, blockIdx.x * 128,
                       z * kslice, (z + 1) * kslice, lds);
}

// ---------------------------------------------------------------------------
// Weight transpose tile: W[K][N] fp32 -> WT[N][K] bf16, 64x64 tile at (kt,nt).
// ---------------------------------------------------------------------------
__device__ __forceinline__ void wt_tile(const float* __restrict__ src,
                                        ushort_t* __restrict__ dst,
                                        int K, int N, int kt, int nt,
                                        float (*T)[65], int tid)
{
    #pragma unroll
    for (int i = 0; i < 4; ++i) {
        const int e = tid + i * 256;
        const int r = e >> 4;
        const int c = (e & 15) * 4;
        const float4 f = *(const float4*)&src[(size_t)(kt + r) * N + nt + c];
        T[c + 0][r] = f.x; T[c + 1][r] = f.y; T[c + 2][r] = f.z; T[c + 3][r] = f.w;
    }
    __syncthreads();
    #pragma unroll
    for (int i = 0; i < 4; ++i) {
        const int e = tid + i * 256;
        const int n = e >> 4;
        const int kc = (e & 15) * 4;
        ushort4 o;
        o.x = f2bf(T[n][kc + 0]); o.y = f2bf(T[n][kc + 1]);
        o.z = f2bf(T[n][kc + 2]); o.w = f2bf(T[n][kc + 3]);
        *(ushort4*)&dst[(size_t)(nt + n) * K + kt + kc] = o;
    }
}

// ---------------------------------------------------------------------------
// prep: blocks 0..431 = early weight transposes (Wq,Wk,Wv; 144 tiles each);
//       blocks 432..1967 = src fp32->bf16 (1536 blocks).
// Late wt (Wo/W1/W2) lives in the qkv_bias dispatch (r11: co-dispatch with
// VALU-bound work; in prep it serialized).
// ---------------------------------------------------------------------------
__global__ __launch_bounds__(256)
void prep_kernel(const float* __restrict__ Wq, const float* __restrict__ Wk,
                 const float* __restrict__ Wv,
                 ushort_t* wqT, ushort_t* wkT, ushort_t* wvT,
                 const float* __restrict__ src, ushort_t* __restrict__ sb)
{
    __shared__ float T[64][65];
    const int bid = blockIdx.x;
    const int tid = threadIdx.x;

    if (bid < 432) {
        const int wz = bid / 144, t = bid - wz * 144;
        const float* s = (wz == 0) ? Wq : (wz == 1) ? Wk : Wv;
        ushort_t*   d = (wz == 0) ? wqT : (wz == 1) ? wkT : wvT;
        wt_tile(s, d, kD, kD, (t % 12) * 64, (t / 12) * 64, T, tid);
    } else {
        const int i = (bid - 432) * 256 + tid;
        const float4 f = ((const float4*)src)[i];
        ushort4 o;
        o.x = f2bf(f.x); o.y = f2bf(f.y); o.z = f2bf(f.z); o.w = f2bf(f.w);
        ((ushort4*)sb)[i] = o;
    }
}

// ---------------------------------------------------------------------------
// Shared-memory layouts for the fused kernels.
// ---------------------------------------------------------------------------
struct BiasSmem {                 // 27312 B
    float P[32][16];              // [u] = {A,B,C,0, W2[0..11]}
    float pb2l[12];
    float qxl[16], qyl[16], kxl[64], kyl[64];
    ushort_t Btile[12 * 1024];
};
struct AttnSmem {                 // 8960 B (Ob rows padded 64->68:
    ushort_t Ob[4][16][68];       //  stride 136 B spreads the 4 fq-lanes to
    float    Ll[4][16];           //  banks +0/8/16/24 -> conflict-free,
};                                //  verified r10: SQ_LDS_BANK_CONFLICT = 0)

// ---------------------------------------------------------------------------
// Relative-position bias tile body (-4 shift folded).
// Thread remap (q=tid>>4, fq2=(tid>>2)&3, n=tid&3): 4 outputs land in 4
// CONSECUTIVE Btile slots -> 12 ushort4 stores (bank-balanced).
// Slot layout matches the swapped-QK attention fragment.
// ---------------------------------------------------------------------------
__device__ __forceinline__ void bias_body(int bid, BiasSmem& S,
                 const float* __restrict__ sx, const float* __restrict__ sy,
                 const float* __restrict__ P1, const float* __restrict__ pb1,
                 const float* __restrict__ P2, const float* __restrict__ pb2,
                 ushort_t* __restrict__ biasb)
{
    const int b  = bid >> 10;
    const int qt = (bid >> 4) & 63;
    const int kt = bid & 15;
    const int tid = threadIdx.x;

    if (tid < 32) {
        S.P[tid][0] = P1[tid];
        S.P[tid][1] = P1[32 + tid];
        S.P[tid][2] = pb1[tid];
        S.P[tid][3] = 0.f;
    }
    for (int e = tid; e < 384; e += 256) S.P[e / 12][4 + e % 12] = P2[e];
    if (tid < 12) S.pb2l[tid] = pb2[tid];
    if (tid < 16) { S.qxl[tid] = sx[b * kL + qt * 16 + tid];
                    S.qyl[tid] = sy[b * kL + qt * 16 + tid]; }
    if (tid < 64) { S.kxl[tid] = sx[b * kL + kt * 64 + tid];
                    S.kyl[tid] = sy[b * kL + kt * 64 + tid]; }
    __syncthreads();

    const int q   = tid >> 4;         // q row 0..15
    const int fq2 = (tid >> 2) & 3;   // k-granule high (reader's fq)
    const int nn  = tid & 3;          // 16-key block
    const float xi = S.qxl[q], yi = S.qyl[q];

    float rx[4], ry[4];
    #pragma unroll
    for (int r = 0; r < 4; ++r) {
        const int kk = nn * 16 + fq2 * 4 + r;
        rx[r] = fminf(fmaxf(xi - S.kxl[kk], -1000.f), 1000.f) * 1e-3f;
        ry[r] = fminf(fmaxf(yi - S.kyl[kk], -1000.f), 1000.f) * 1e-3f;
    }

    float acc[4][12] = {};
    #pragma unroll 4
    for (int u = 0; u < 32; ++u) {
        const float4 pc = *(const float4*)&S.P[u][0];
        const float4 w0 = *(const float4*)&S.P[u][4];
        const float4 w1 = *(const float4*)&S.P[u][8];
        const float4 w2 = *(const float4*)&S.P[u][12];
        float t[4];
        #pragma unroll
        for (int r = 0; r < 4; ++r)
            t[r] = fmaxf(fmaf(rx[r], pc.x, fmaf(ry[r], pc.y, pc.z)), 0.f);
        #pragma unroll
        for (int r = 0; r < 4; ++r) {
            acc[r][0]  = fmaf(t[r], w0.x, acc[r][0]);
            acc[r][1]  = fmaf(t[r], w0.y, acc[r][1]);
            acc[r][2]  = fmaf(t[r], w0.z, acc[r][2]);
            acc[r][3]  = fmaf(t[r], w0.w, acc[r][3]);
            acc[r][4]  = fmaf(t[r], w1.x, acc[r][4]);
            acc[r][5]  = fmaf(t[r], w1.y, acc[r][5]);
            acc[r][6]  = fmaf(t[r], w1.z, acc[r][6]);
            acc[r][7]  = fmaf(t[r], w1.w, acc[r][7]);
            acc[r][8]  = fmaf(t[r], w2.x, acc[r][8]);
            acc[r][9]  = fmaf(t[r], w2.y, acc[r][9]);
            acc[r][10] = fmaf(t[r], w2.z, acc[r][10]);
            acc[r][11] = fmaf(t[r], w2.w, acc[r][11]);
        }
    }

    ushort_t* wbase = &S.Btile[fq2 * 256 + q * 16 + nn * 4];
    #pragma unroll
    for (int h = 0; h < 12; ++h) {
        const float pb = S.pb2l[h] - 4.0f;    // fixed softmax shift folded in
        ushort4 o;
        o.x = f2bf(acc[0][h] + pb);
        o.y = f2bf(acc[1][h] + pb);
        o.z = f2bf(acc[2][h] + pb);
        o.w = f2bf(acc[3][h] + pb);
        *(ushort4*)(wbase + h * 1024) = o;
    }
    __syncthreads();

    #pragma unroll
    for (int i = 0; i < 6; ++i) {
        const int off = (i * 256 + tid) * 8;
        const int h = off >> 10;
        const int inner = off & 1023;
        ushort_t* dst = biasb +
            (((size_t)(b * kNH + h) * 64 + qt) * 16 + kt) * 1024 + inner;
        *(uint4*)dst = *(const uint4*)&S.Btile[off];
    }
}

// ---------------------------------------------------------------------------
// Fused QKV GEMM (0..287) + bias table (288..2335) + late weight transposes
// (2336..3631).  wt blocks co-dispatched here (r11 verified ~free: this
// dispatch is VALU-bound, wt is HBM-latency-bound).  V projection writes
// directly transposed+key-permuted to vt (OUTMODE=2).
// ---------------------------------------------------------------------------
constexpr size_t kQkvSmem =
    sizeof(BiasSmem) > 34816 ? sizeof(BiasSmem) : 34816;

__global__ __launch_bounds__(256)
void qkv_bias_kernel(const ushort_t* __restrict__ A,
                     const ushort_t* wq, const ushort_t* wk, const ushort_t* wv,
                     const float* bq, const float* bk, const float* bv,
                     ushort_t* q, ushort_t* k, ushort_t* vt,
                     const float* __restrict__ sx, const float* __restrict__ sy,
                     const float* __restrict__ P1, const float* __restrict__ pb1,
                     const float* __restrict__ P2, const float* __restrict__ pb2,
                     ushort_t* __restrict__ biasb,
                     const float* __restrict__ Wo, const float* __restrict__ W1,
                     const float* __restrict__ W2,
                     ushort_t* woT, ushort_t* w1T, ushort_t* w2T)
{
    __shared__ __align__(16) char smem[kQkvSmem];
    const int bid = blockIdx.x;

    if (bid < 288) {
        const int z = bid / 96, rem = bid - z * 96;
        const int bx = rem % 6, by = rem / 6;
        if (z == 0)
            gemm_body<0, 1, 1>(A, wq, bq, q,  kD, kD,
                               by * 128, bx * 128, 0, kD, (ushort_t*)smem);
        else if (z == 1)
            gemm_body<0, 1, 1>(A, wk, bk, k,  kD, kD,
                               by * 128, bx * 128, 0, kD, (ushort_t*)smem);
        else
            gemm_body<0, 2, 1>(A, wv, bv, vt, kD, kD,
                               by * 128, bx * 128, 0, kD, (ushort_t*)smem);
    } else if (bid < 2336) {
        bias_body(bid - 288, *(BiasSmem*)smem, sx, sy, P1, pb1, P2, pb2, biasb);
    } else {
        float (*T)[65] = (float(*)[65])smem;
        const int t = bid - 2336;
        if (t < 144)      wt_tile(Wo, woT, kD,  kD,  (t % 12) * 64, (t / 12) * 64, T, threadIdx.x);
        else if (t < 720) { const int t2 = t - 144;
                            wt_tile(W1, w1T, kD,  kFF, (t2 % 12) * 64, (t2 / 12) * 64, T, threadIdx.x); }
        else              { const int t2 = t - 720;
                            wt_tile(W2, w2T, kFF, kD,  (t2 % 48) * 64, (t2 / 48) * 64, T, threadIdx.x); }
    }
}

// ---------------------------------------------------------------------------
// Pure attention kernel (1536 blocks).  ROUND-12: V prefetched one t-iter
// ahead (vc/vn double-set) alongside K/bias — V was the last load issued in
// the same iteration it's consumed (only ~QK+exp of cover for 200-400cy L2
// latency).  Now all loads for iter t+1 issue right after iter t's QK MFMAs
// and are covered by exp + PV + next-QK.  Block = (b,h) x 16-q-row tile;
// 4 waves = 4 K-quarters; 4-way in-block combine; swapped QK^T + lane-local
// softmax + permuted-V; bijective XCD swizzle (1536 = 8*192); no forced
// occupancy bound (r4 lesson).
// ---------------------------------------------------------------------------
__global__ __launch_bounds__(256)
void attn_kernel(const ushort_t* __restrict__ qg, const ushort_t* __restrict__ kg,
                 const ushort_t* __restrict__ vt, const ushort_t* __restrict__ biasb,
                 ushort_t* __restrict__ og)
{
    __shared__ __align__(16) AttnSmem S;
    const int bid = blockIdx.x;
    const int tid = threadIdx.x;

    const int swz  = (bid & 7) * 192 + (bid >> 3);
    const int bh   = swz >> 6;        // 0..23
    const int qt   = swz & 63;        // 16-row q tile index
    const int b  = bh / kNH, h = bh - b * kNH;
    const int z  = tid >> 6;          // wave = K quarter
    const int lane = tid & 63;
    const int fl = lane & 15, fq = lane >> 4;
    const int q0 = qt * 16;
    const int kbeg = z * 256;

    const size_t qoff = (size_t)(b * kL + q0 + fl) * kD + h * kDK + fq * 8;
    const bf16x8 aq0 = *(const bf16x8*)(qg + qoff);
    const bf16x8 aq1 = *(const bf16x8*)(qg + qoff + 32);

    const ushort_t* kbase = kg + (size_t)(b * kL) * kD + h * kDK + fq * 8;
    const ushort_t* vbase = vt + (size_t)(bh * 64) * kL + fq * 8;
    const ushort_t* btile = biasb +
        ((size_t)(bh * 64 + qt) * 16 + z * 4) * 1024 + lane * 16;

    f32x4 accO[4] = {};
    float l_loc = 0.f;                // lane-local l for q = q0+fl

    bf16x8 kc[4][2], vc[4][2];
    uint4 bc0, bc1;
    {
        #pragma unroll
        for (int n = 0; n < 4; ++n) {
            const ushort_t* kr = kbase + (size_t)(kbeg + n * 16 + fl) * kD;
            kc[n][0] = *(const bf16x8*)kr;
            kc[n][1] = *(const bf16x8*)(kr + 32);
            const ushort_t* vr = vbase + (size_t)(n * 16 + fl) * kL + kbeg;
            vc[n][0] = *(const bf16x8*)vr;
            vc[n][1] = *(const bf16x8*)(vr + 32);
        }
        bc0 = *(const uint4*)btile;
        bc1 = *(const uint4*)(btile + 8);
    }

    #pragma unroll
    for (int t = 0; t < 4; ++t) {
        const int k0 = kbeg + t * 64;

        // swapped QK^T: S^T[k][q] — A=K, B=Q (depends only on kc)
        f32x4 Sv[4] = {};
        __builtin_amdgcn_s_setprio(1);
        #pragma unroll
        for (int n = 0; n < 4; ++n) {
            Sv[n] = __builtin_amdgcn_mfma_f32_16x16x32_bf16(kc[n][0], aq0, Sv[n], 0, 0, 0);
            Sv[n] = __builtin_amdgcn_mfma_f32_16x16x32_bf16(kc[n][1], aq1, Sv[n], 0, 0, 0);
        }
        __builtin_amdgcn_s_setprio(0);

        // prefetch ALL of next iter (K, V, bias) — covered by exp + PV + next QK
        bf16x8 kn[4][2], vn[4][2];
        uint4 bn0, bn1;
        if (t < 3) {
            #pragma unroll
            for (int n = 0; n < 4; ++n) {
                const ushort_t* kr = kbase + (size_t)(k0 + 64 + n * 16 + fl) * kD;
                kn[n][0] = *(const bf16x8*)kr;
                kn[n][1] = *(const bf16x8*)(kr + 32);
                const ushort_t* vr = vbase + (size_t)(n * 16 + fl) * kL + k0 + 64;
                vn[n][0] = *(const bf16x8*)vr;
                vn[n][1] = *(const bf16x8*)(vr + 32);
            }
            bn0 = *(const uint4*)(btile + (t + 1) * 1024);
            bn1 = *(const uint4*)(btile + (t + 1) * 1024 + 8);
        }

        ushort_t bu[16];
        *(uint4*)&bu[0] = bc0;
        *(uint4*)&bu[8] = bc1;

        // lane-local softmax + lane-local P fragments (virtual-k ordering
        // matches vt's folded permutation)
        bf16x8 ap0, ap1;
        #pragma unroll
        for (int n = 0; n < 4; ++n)
            #pragma unroll
            for (int r = 0; r < 4; ++r) {
                const float e = __expf(fmaf(Sv[n][r], 0.125f, bf2f(bu[n * 4 + r])));
                l_loc += e;
                const short pb = (short)f2bf(e);
                if (n < 2) ap0[n * 4 + r] = pb;
                else       ap1[(n - 2) * 4 + r] = pb;
            }

        __builtin_amdgcn_s_setprio(1);
        #pragma unroll
        for (int n = 0; n < 4; ++n) {
            accO[n] = __builtin_amdgcn_mfma_f32_16x16x32_bf16(ap0, vc[n][0], accO[n], 0, 0, 0);
            accO[n] = __builtin_amdgcn_mfma_f32_16x16x32_bf16(ap1, vc[n][1], accO[n], 0, 0, 0);
        }
        __builtin_amdgcn_s_setprio(0);

        if (t < 3) {
            #pragma unroll
            for (int n = 0; n < 4; ++n) {
                kc[n][0] = kn[n][0]; kc[n][1] = kn[n][1];
                vc[n][0] = vn[n][0]; vc[n][1] = vn[n][1];
            }
            bc0 = bn0; bc1 = bn1;
        }
    }

    // full l for q=fl within this wave's K quarter: reduce across fq groups
    float l = l_loc;
    l += __shfl_xor(l, 16, 64);
    l += __shfl_xor(l, 32, 64);

    // inv for output rows q = fq*4+r (held by lane fq*4+r after reduction)
    float inv[4];
    #pragma unroll
    for (int r = 0; r < 4; ++r)
        inv[r] = 1.0f / __shfl(l, fq * 4 + r, 64);

    #pragma unroll
    for (int n = 0; n < 4; ++n)
        #pragma unroll
        for (int r = 0; r < 4; ++r)
            S.Ob[z][fq * 4 + r][n * 16 + fl] = f2bf(accO[n][r] * inv[r]);
    if (lane < 16) S.Ll[z][lane] = l;
    __syncthreads();

    if (tid < 128) {
        const int ri = tid >> 3;            // 0..15 (q row)
        const int d0 = (tid & 7) * 8;       // 8 cols each
        const float w0 = S.Ll[0][ri], w1 = S.Ll[1][ri];
        const float w2 = S.Ll[2][ri], w3 = S.Ll[3][ri];
        const float winv = 1.0f / (w0 + w1 + w2 + w3);
        const float c0 = w0 * winv, c1 = w1 * winv;
        const float c2 = w2 * winv, c3 = w3 * winv;

        ushort_t o[8];
        #pragma unroll
        for (int j = 0; j < 8; ++j)
            o[j] = f2bf(fmaf(c0, bf2f(S.Ob[0][ri][d0 + j]),
                        fmaf(c1, bf2f(S.Ob[1][ri][d0 + j]),
                        fmaf(c2, bf2f(S.Ob[2][ri][d0 + j]),
                             c3 * bf2f(S.Ob[3][ri][d0 + j])))));
        ushort_t* dp = og + (size_t)(b * kL + q0 + ri) * kD + h * kDK + d0;
        *(uint4*)dp = *(const uint4*)o;
    }
}

// ---------------------------------------------------------------------------
// Residual + split-K reduce + bias + LayerNorm.
// ---------------------------------------------------------------------------
template<int NPART, int DUAL>
__global__ __launch_bounds__(256)
void ln_kernel(const float* __restrict__ a, const float* __restrict__ parts,
               const float* __restrict__ bias,
               const float* __restrict__ g, const float* __restrict__ be,
               float* __restrict__ out, ushort_t* __restrict__ out_bf)
{
    const int row = blockIdx.x;
    const int tid = threadIdx.x;
    const float* pa = a + (size_t)row * kD;
    constexpr size_t NTOK = (size_t)kRows * kD;

    float v[3];
    float s = 0.f, sq = 0.f;
    #pragma unroll
    for (int i = 0; i < 3; ++i) {
        const int d = tid + i * 256;
        float t = pa[d] + bias[d];
        #pragma unroll
        for (int p = 0; p < NPART; ++p)
            t += parts[p * NTOK + (size_t)row * kD + d];
        v[i] = t;
        s  += t;
        sq += t * t;
    }
    #pragma unroll
    for (int off = 32; off > 0; off >>= 1) {
        s  += __shfl_down(s, off);
        sq += __shfl_down(sq, off);
    }
    __shared__ float bs[4], bq2[4];
    if ((tid & 63) == 0) { bs[tid >> 6] = s; bq2[tid >> 6] = sq; }
    __syncthreads();
    const float ts = bs[0] + bs[1] + bs[2] + bs[3];
    const float tq = bq2[0] + bq2[1] + bq2[2] + bq2[3];
    const float invn = 1.0f / (float)kD;
    const float mean = ts * invn;
    const float var  = tq * invn - mean * mean;
    const float rstd = rsqrtf(var + kEPS);

    float* po = out + (size_t)row * kD;
    #pragma unroll
    for (int i = 0; i < 3; ++i) {
        const int d = tid + i * 256;
        const float o = (v[i] - mean) * rstd * g[d] + be[d];
        po[d] = o;
        if (DUAL) out_bf[(size_t)row * kD + d] = f2bf(o);
    }
}

// ---------------------------------------------------------------------------
extern "C" void kernel_launch(void* const* d_in, const int* in_sizes, int n_in,
                              void* d_out, int out_size, void* d_ws, size_t ws_size,
                              hipStream_t stream)
{
    const float* src = (const float*)d_in[0];
    const float* sx  = (const float*)d_in[1];
    const float* sy  = (const float*)d_in[2];
    const float* Wq  = (const float*)d_in[3];  const float* bq  = (const float*)d_in[4];
    const float* Wk  = (const float*)d_in[5];  const float* bk  = (const float*)d_in[6];
    const float* Wv  = (const float*)d_in[7];  const float* bv  = (const float*)d_in[8];
    const float* Wo  = (const float*)d_in[9];  const float* bo  = (const float*)d_in[10];
    const float* P1  = (const float*)d_in[11]; const float* pb1 = (const float*)d_in[12];
    const float* P2  = (const float*)d_in[13]; const float* pb2 = (const float*)d_in[14];
    const float* W1  = (const float*)d_in[15]; const float* b1  = (const float*)d_in[16];
    const float* W2  = (const float*)d_in[17]; const float* b2  = (const float*)d_in[18];
    const float* g1  = (const float*)d_in[19]; const float* be1 = (const float*)d_in[20];
    const float* g2  = (const float*)d_in[21]; const float* be2 = (const float*)d_in[22];

    // ---- workspace arena (ushort units) ----
    constexpr size_t W768  = 768u * 768u;
    constexpr size_t W3072 = 768u * 3072u;
    constexpr size_t NTOK  = (size_t)kRows * kD;

    ushort_t* wsu = (ushort_t*)d_ws;
    ushort_t* wqT = wsu;
    ushort_t* wkT = wqT + W768;
    ushort_t* wvT = wkT + W768;
    ushort_t* qb  = wvT + W768;          // Q; dead after attn -> xbf
    ushort_t* kb  = qb + NTOK;
    ushort_t* vb  = kb + NTOK;           // (slot unused; V goes direct to vtb)
    ushort_t* sb  = vb + NTOK;           // src_bf -> attn out
    ushort_t* vtb = sb + NTOK;
    ushort_t* biasb = vtb + NTOK;        // 50 MB bias; dead after attn
    float*    xb    = (float*)(biasb + W768 + 2 * W3072);
    ushort_t* h1bf  = (ushort_t*)(xb + NTOK);
    ushort_t* xbf   = qb;

    const size_t h1off   = (size_t)(h1bf - wsu);
    const size_t bigNeed = (h1off + 20 * NTOK + W768 + 2 * W3072) * 2;
    const bool   big     = ws_size >= bigNeed;

    float*    s2p;
    float*    ff2p;
    ushort_t* scratch;
    int npWo, npFF;
    if (big) {
        s2p     = (float*)h1bf;
        ff2p    = (float*)(h1bf + 8 * NTOK);
        scratch = h1bf + 20 * NTOK;
        npWo = 4; npFF = 6;
    } else {
        s2p     = (float*)h1bf;
        ff2p    = (float*)(h1bf + 4 * NTOK);
        scratch = (ushort_t*)(ff2p + 3 * NTOK);
        npWo = 2; npFF = 3;
    }
    ushort_t* woT2 = scratch;
    ushort_t* w1T2 = woT2 + W768;
    ushort_t* w2T2 = w1T2 + W3072;

    const dim3 blk(256);

    // 1. early weight transposes + src->bf16 (fused)
    prep_kernel<<<dim3(1968), blk, 0, stream>>>(Wq, Wk, Wv, wqT, wkT, wvT, src, sb);

    // 2. QKV projection + bias table + late weight transposes (co-dispatched)
    qkv_bias_kernel<<<dim3(3632), blk, 0, stream>>>(
        sb, wqT, wkT, wvT, bq, bk, bv, qb, kb, vtb,
        sx, sy, P1, pb1, P2, pb2, biasb, Wo, W1, W2, woT2, w1T2, w2T2);

    // 3. pure attention (1536 blocks = 24 bh x 64 q-tiles, 4-way K-split)
    attn_kernel<<<dim3(1536), blk, 0, stream>>>(qb, kb, vtb, biasb, sb);

    // 4. out-projection, split-K -> fp32 partials
    gemm_splitk_kernel<<<dim3(kD / 128, kRows / 128, npWo), blk, 0, stream>>>(
        sb, woT2, s2p, kD, kD, kD / npWo);

    // 5. LN1: x = LN(src + bo + partials), fp32 + bf16
    if (big) ln_kernel<4, 1><<<dim3(kRows), blk, 0, stream>>>(src, s2p, bo, g1, be1, xb, xbf);
    else     ln_kernel<2, 1><<<dim3(kRows), blk, 0, stream>>>(src, s2p, bo, g1, be1, xb, xbf);

    // 6. FFN1: relu(x @ W1 + b1) -> bf16
    gemm_kernel<1, 1><<<dim3(kFF / 128, kRows / 128), blk, 0, stream>>>(
        xbf, w1T2, b1, h1bf, kFF, kD);

    // 7. FFN2, split-K -> fp32 partials
    gemm_splitk_kernel<<<dim3(kD / 128, kRows / 128, npFF), blk, 0, stream>>>(
        h1bf, w2T2, ff2p, kD, kFF, kFF / npFF);

    // 8. LN2: out = LN(x + b2 + partials)
    if (big) ln_kernel<6, 0><<<dim3(kRows), blk, 0, stream>>>(xb, ff2p, b2, g2, be2,
                                                              (float*)d_out, nullptr);
    else     ln_kernel<3, 0><<<dim3(kRows), blk, 0, stream>>>(xb, ff2p, b2, g2, be2,
                                                              (float*)d_out, nullptr);
}

// Round 14
// 274.968 us; speedup vs baseline: 1.0178x; 1.0011x over previous
//
#include <hip/hip_runtime.h>
#include <math.h>

typedef unsigned short ushort_t;
typedef __attribute__((ext_vector_type(8))) short bf16x8;
typedef __attribute__((ext_vector_type(4))) float f32x4;

constexpr int kD      = 768;
constexpr int kNH     = 12;
constexpr int kDK     = 64;
constexpr int kFF     = 3072;
constexpr int kL      = 1024;
constexpr int kRows   = 2048;     // B * L
constexpr float kEPS  = 1e-5f;

__device__ __forceinline__ ushort_t f2bf(float f) {
    union { float f; unsigned u; } v; v.f = f;
    unsigned r = (v.u + 0x7fffu + ((v.u >> 16) & 1u)) >> 16;
    return (ushort_t)r;
}
__device__ __forceinline__ float bf2f(ushort_t u) {
    union { unsigned u; float f; } v; v.u = ((unsigned)u) << 16; return v.f;
}

#define GL_LDS(gp, lp) __builtin_amdgcn_global_load_lds( \
    (const __attribute__((address_space(1))) void*)(gp), \
    (__attribute__((address_space(3))) void*)(lp), 16, 0, 0)

// ---------------------------------------------------------------------------
// bf16 MFMA GEMM body: 128x128 tile, BK=32, 4 waves, double-buffered LDS.
// Epilogue modes:
//   OUTMODE 0: fp32 direct stores (split-K partials).
//   OUTMODE 1: bf16 via LDS staging -> coalesced uint4 row stores.
//   OUTMODE 2: bf16 transposed via LDS -> V^T tile direct to vt, with the
//              attn-fragment key permutation folded in (see attn kernel).
// ROUND-13/14: staging stride 136 -> 140 ushorts (70 dwords, 70%32=6,
// gcd(6,32)=2).  At 136 (68 dwords = 4 mod 32) the staging writes were
// ~4-way bank-serialized and read-out b128 starts hit only 8 banks (the
// remaining 2.47M SQ_LDS_BANK_CONFLICT in qkv_bias/FFN1).  At 140, fl
// spreads over 16 distinct banks, fq over 4 more -> ~2-way (free, m136).
// LDS supplied by caller: >= 17920 ushorts.  Staging tile [128][140].
// ---------------------------------------------------------------------------
template<int RELU, int OUTMODE, int ADDBIAS>
__device__ __forceinline__ void gemm_body(const ushort_t* __restrict__ A,
                                          const ushort_t* __restrict__ WT,
                                          const float* __restrict__ bias,
                                          void* __restrict__ Cout,
                                          int N, int K, int row0, int col0,
                                          int kbeg, int kend, ushort_t* lds)
{
    const int tid  = threadIdx.x;
    const int lane = tid & 63;
    const int wave = tid >> 6;
    const int wrow = (wave & 1) * 64;
    const int wcol = (wave >> 1) * 64;

    const int srow = wave * 16 + (lane >> 2);
    const int sk   = (lane & 3) * 8;
    const ushort_t* ga0 = A  + (size_t)(row0 + srow)      * K + sk;
    const ushort_t* ga1 = A  + (size_t)(row0 + srow + 64) * K + sk;
    const ushort_t* gb0 = WT + (size_t)(col0 + srow)      * K + sk;
    const ushort_t* gb1 = WT + (size_t)(col0 + srow + 64) * K + sk;

    const int wo = wave * 512;
    const int fl = lane & 15, fq = lane >> 4;

    f32x4 acc[4][4] = {};

    {
        ushort_t* b0 = lds;
        GL_LDS(ga0 + kbeg, b0 + wo);
        GL_LDS(ga1 + kbeg, b0 + 2048 + wo);
        GL_LDS(gb0 + kbeg, b0 + 4096 + wo);
        GL_LDS(gb1 + kbeg, b0 + 4096 + 2048 + wo);
    }
    __syncthreads();

    int cur = 0;
    for (int k0 = kbeg; k0 < kend; k0 += 32) {
        ushort_t* bs = lds + (cur ? 8192 : 0);
        ushort_t* bn = lds + (cur ? 0 : 8192);

        if (k0 + 32 < kend) {
            GL_LDS(ga0 + k0 + 32, bn + wo);
            GL_LDS(ga1 + k0 + 32, bn + 2048 + wo);
            GL_LDS(gb0 + k0 + 32, bn + 4096 + wo);
            GL_LDS(gb1 + k0 + 32, bn + 4096 + 2048 + wo);
        }

        bf16x8 av[4], bv[4];
        #pragma unroll
        for (int i = 0; i < 4; ++i) {
            av[i] = *(const bf16x8*)(bs + (wrow + i * 16 + fl) * 32 + fq * 8);
            bv[i] = *(const bf16x8*)(bs + 4096 + (wcol + i * 16 + fl) * 32 + fq * 8);
        }
        #pragma unroll
        for (int mi = 0; mi < 4; ++mi)
            #pragma unroll
            for (int ni = 0; ni < 4; ++ni)
                acc[mi][ni] = __builtin_amdgcn_mfma_f32_16x16x32_bf16(
                    av[mi], bv[ni], acc[mi][ni], 0, 0, 0);

        __syncthreads();
        cur ^= 1;
    }

    if (OUTMODE == 0) {
        #pragma unroll
        for (int mi = 0; mi < 4; ++mi) {
            const int m = wrow + mi * 16 + fq * 4;
            #pragma unroll
            for (int ni = 0; ni < 4; ++ni) {
                const int n = wcol + ni * 16 + fl;
                const float bb = ADDBIAS ? bias[col0 + n] : 0.f;
                #pragma unroll
                for (int r = 0; r < 4; ++r) {
                    float v = acc[mi][ni][r] + bb;
                    if (RELU) v = fmaxf(v, 0.f);
                    ((float*)Cout)[(size_t)(row0 + m + r) * N + col0 + n] = v;
                }
            }
        }
    } else {
        ushort_t* T = lds;            // [128][140] staging tile
        #pragma unroll
        for (int mi = 0; mi < 4; ++mi) {
            const int m = wrow + mi * 16 + fq * 4;
            #pragma unroll
            for (int ni = 0; ni < 4; ++ni) {
                const int n = wcol + ni * 16 + fl;
                const float bb = ADDBIAS ? bias[col0 + n] : 0.f;
                #pragma unroll
                for (int r = 0; r < 4; ++r) {
                    float v = acc[mi][ni][r] + bb;
                    if (RELU) v = fmaxf(v, 0.f);
                    if (OUTMODE == 1) T[(m + r) * 140 + n] = f2bf(v);
                    else              T[n * 140 + (m + r)] = f2bf(v);
                }
            }
        }
        __syncthreads();
        const int row = tid >> 1;     // token (mode1) / feature (mode2)
        const int seg = tid & 1;      // 64-elem half
        const ushort_t* sp = T + row * 140 + seg * 64;
        if (OUTMODE == 1) {
            ushort_t* dp = (ushort_t*)Cout + (size_t)(row0 + row) * N + col0 + seg * 64;
            #pragma unroll
            for (int i = 0; i < 8; ++i)
                *(uint4*)(dp + i * 8) = *(const uint4*)(sp + i * 8);
        } else {
            const int bb2 = row0 >> 10;            // batch (tiles never straddle)
            const int c   = col0 + row;            // global feature 0..767
            const int vtr = (bb2 * kNH + (c >> 6)) * kDK + (c & 63);
            ushort_t* dp = (ushort_t*)Cout + (size_t)vtr * kL + (row0 & 1023) + seg * 64;
            // permuted gather: output position p (within each 32-token block)
            // holds actual token pi(p); granule (4-token) map pg -> ga:
            //   ga = (pg&1)*4 + (pg>>1)
            uint2 w[16];
            #pragma unroll
            for (int g = 0; g < 16; ++g) {
                const int h32 = g >> 3, pg = g & 7;
                const int srcTok = h32 * 32 + ((pg & 1) * 4 + (pg >> 1)) * 4;
                w[g] = *(const uint2*)(sp + srcTok);
            }
            #pragma unroll
            for (int i = 0; i < 8; ++i) {
                uint4 o; o.x = w[2*i].x; o.y = w[2*i].y;
                o.z = w[2*i+1].x; o.w = w[2*i+1].y;
                *(uint4*)(dp + i * 8) = o;
            }
        }
    }
}

template<int RELU, int OUTMODE>
__global__ __launch_bounds__(256)
void gemm_kernel(const ushort_t* __restrict__ A, const ushort_t* __restrict__ WT,
                 const float* __restrict__ bias, void* __restrict__ Cout,
                 int N, int K)
{
    __shared__ ushort_t lds[17920];
    gemm_body<RELU, OUTMODE, 1>(A, WT, bias, Cout, N, K,
                                blockIdx.y * 128, blockIdx.x * 128, 0, K, lds);
}

__global__ __launch_bounds__(256)
void gemm_splitk_kernel(const ushort_t* __restrict__ A, const ushort_t* __restrict__ WT,
                        float* __restrict__ parts, int N, int K, int kslice)
{
    __shared__ ushort_t lds[16384];
    const int z = blockIdx.z;
    float* out = parts + (size_t)z * kRows * N;
    gemm_body<0, 0, 0>(A, WT, nullptr, out, N, K,
                       blockIdx.y * 128, blockIdx.x * 128,
                       z * kslice, (z + 1) * kslice, lds);
}

// ---------------------------------------------------------------------------
// Weight transpose tile: W[K][N] fp32 -> WT[N][K] bf16, 64x64 tile at (kt,nt).
// ---------------------------------------------------------------------------
__device__ __forceinline__ void wt_tile(const float* __restrict__ src,
                                        ushort_t* __restrict__ dst,
                                        int K, int N, int kt, int nt,
                                        float (*T)[65], int tid)
{
    #pragma unroll
    for (int i = 0; i < 4; ++i) {
        const int e = tid + i * 256;
        const int r = e >> 4;
        const int c = (e & 15) * 4;
        const float4 f = *(const float4*)&src[(size_t)(kt + r) * N + nt + c];
        T[c + 0][r] = f.x; T[c + 1][r] = f.y; T[c + 2][r] = f.z; T[c + 3][r] = f.w;
    }
    __syncthreads();
    #pragma unroll
    for (int i = 0; i < 4; ++i) {
        const int e = tid + i * 256;
        const int n = e >> 4;
        const int kc = (e & 15) * 4;
        ushort4 o;
        o.x = f2bf(T[n][kc + 0]); o.y = f2bf(T[n][kc + 1]);
        o.z = f2bf(T[n][kc + 2]); o.w = f2bf(T[n][kc + 3]);
        *(ushort4*)&dst[(size_t)(nt + n) * K + kt + kc] = o;
    }
}

// ---------------------------------------------------------------------------
// prep: blocks 0..431 = early weight transposes (Wq,Wk,Wv; 144 tiles each);
//       blocks 432..1967 = src fp32->bf16 (1536 blocks).
// Late wt (Wo/W1/W2) lives in the qkv_bias dispatch (r11: co-dispatch with
// VALU-bound work; in prep it serialized).
// ---------------------------------------------------------------------------
__global__ __launch_bounds__(256)
void prep_kernel(const float* __restrict__ Wq, const float* __restrict__ Wk,
                 const float* __restrict__ Wv,
                 ushort_t* wqT, ushort_t* wkT, ushort_t* wvT,
                 const float* __restrict__ src, ushort_t* __restrict__ sb)
{
    __shared__ float T[64][65];
    const int bid = blockIdx.x;
    const int tid = threadIdx.x;

    if (bid < 432) {
        const int wz = bid / 144, t = bid - wz * 144;
        const float* s = (wz == 0) ? Wq : (wz == 1) ? Wk : Wv;
        ushort_t*   d = (wz == 0) ? wqT : (wz == 1) ? wkT : wvT;
        wt_tile(s, d, kD, kD, (t % 12) * 64, (t / 12) * 64, T, tid);
    } else {
        const int i = (bid - 432) * 256 + tid;
        const float4 f = ((const float4*)src)[i];
        ushort4 o;
        o.x = f2bf(f.x); o.y = f2bf(f.y); o.z = f2bf(f.z); o.w = f2bf(f.w);
        ((ushort4*)sb)[i] = o;
    }
}

// ---------------------------------------------------------------------------
// Shared-memory layouts for the fused kernels.
// ---------------------------------------------------------------------------
struct BiasSmem {                 // 27312 B
    float P[32][16];              // [u] = {A,B,C,0, W2[0..11]}
    float pb2l[12];
    float qxl[16], qyl[16], kxl[64], kyl[64];
    ushort_t Btile[12 * 1024];
};
struct AttnSmem {                 // 8960 B (Ob rows padded 64->68:
    ushort_t Ob[4][16][68];       //  stride 136 B spreads the 4 fq-lanes to
    float    Ll[4][16];           //  banks +0/8/16/24 -> conflict-free,
};                                //  verified r10: SQ_LDS_BANK_CONFLICT = 0)

// ---------------------------------------------------------------------------
// Relative-position bias tile body (-4 shift folded).
// Thread remap (q=tid>>4, fq2=(tid>>2)&3, n=tid&3): 4 outputs land in 4
// CONSECUTIVE Btile slots -> 12 ushort4 stores (bank-balanced).
// Slot layout matches the swapped-QK attention fragment.
// ---------------------------------------------------------------------------
__device__ __forceinline__ void bias_body(int bid, BiasSmem& S,
                 const float* __restrict__ sx, const float* __restrict__ sy,
                 const float* __restrict__ P1, const float* __restrict__ pb1,
                 const float* __restrict__ P2, const float* __restrict__ pb2,
                 ushort_t* __restrict__ biasb)
{
    const int b  = bid >> 10;
    const int qt = (bid >> 4) & 63;
    const int kt = bid & 15;
    const int tid = threadIdx.x;

    if (tid < 32) {
        S.P[tid][0] = P1[tid];
        S.P[tid][1] = P1[32 + tid];
        S.P[tid][2] = pb1[tid];
        S.P[tid][3] = 0.f;
    }
    for (int e = tid; e < 384; e += 256) S.P[e / 12][4 + e % 12] = P2[e];
    if (tid < 12) S.pb2l[tid] = pb2[tid];
    if (tid < 16) { S.qxl[tid] = sx[b * kL + qt * 16 + tid];
                    S.qyl[tid] = sy[b * kL + qt * 16 + tid]; }
    if (tid < 64) { S.kxl[tid] = sx[b * kL + kt * 64 + tid];
                    S.kyl[tid] = sy[b * kL + kt * 64 + tid]; }
    __syncthreads();

    const int q   = tid >> 4;         // q row 0..15
    const int fq2 = (tid >> 2) & 3;   // k-granule high (reader's fq)
    const int nn  = tid & 3;          // 16-key block
    const float xi = S.qxl[q], yi = S.qyl[q];

    float rx[4], ry[4];
    #pragma unroll
    for (int r = 0; r < 4; ++r) {
        const int kk = nn * 16 + fq2 * 4 + r;
        rx[r] = fminf(fmaxf(xi - S.kxl[kk], -1000.f), 1000.f) * 1e-3f;
        ry[r] = fminf(fmaxf(yi - S.kyl[kk], -1000.f), 1000.f) * 1e-3f;
    }

    float acc[4][12] = {};
    #pragma unroll 4
    for (int u = 0; u < 32; ++u) {
        const float4 pc = *(const float4*)&S.P[u][0];
        const float4 w0 = *(const float4*)&S.P[u][4];
        const float4 w1 = *(const float4*)&S.P[u][8];
        const float4 w2 = *(const float4*)&S.P[u][12];
        float t[4];
        #pragma unroll
        for (int r = 0; r < 4; ++r)
            t[r] = fmaxf(fmaf(rx[r], pc.x, fmaf(ry[r], pc.y, pc.z)), 0.f);
        #pragma unroll
        for (int r = 0; r < 4; ++r) {
            acc[r][0]  = fmaf(t[r], w0.x, acc[r][0]);
            acc[r][1]  = fmaf(t[r], w0.y, acc[r][1]);
            acc[r][2]  = fmaf(t[r], w0.z, acc[r][2]);
            acc[r][3]  = fmaf(t[r], w0.w, acc[r][3]);
            acc[r][4]  = fmaf(t[r], w1.x, acc[r][4]);
            acc[r][5]  = fmaf(t[r], w1.y, acc[r][5]);
            acc[r][6]  = fmaf(t[r], w1.z, acc[r][6]);
            acc[r][7]  = fmaf(t[r], w1.w, acc[r][7]);
            acc[r][8]  = fmaf(t[r], w2.x, acc[r][8]);
            acc[r][9]  = fmaf(t[r], w2.y, acc[r][9]);
            acc[r][10] = fmaf(t[r], w2.z, acc[r][10]);
            acc[r][11] = fmaf(t[r], w2.w, acc[r][11]);
        }
    }

    ushort_t* wbase = &S.Btile[fq2 * 256 + q * 16 + nn * 4];
    #pragma unroll
    for (int h = 0; h < 12; ++h) {
        const float pb = S.pb2l[h] - 4.0f;    // fixed softmax shift folded in
        ushort4 o;
        o.x = f2bf(acc[0][h] + pb);
        o.y = f2bf(acc[1][h] + pb);
        o.z = f2bf(acc[2][h] + pb);
        o.w = f2bf(acc[3][h] + pb);
        *(ushort4*)(wbase + h * 1024) = o;
    }
    __syncthreads();

    #pragma unroll
    for (int i = 0; i < 6; ++i) {
        const int off = (i * 256 + tid) * 8;
        const int h = off >> 10;
        const int inner = off & 1023;
        ushort_t* dst = biasb +
            (((size_t)(b * kNH + h) * 64 + qt) * 16 + kt) * 1024 + inner;
        *(uint4*)dst = *(const uint4*)&S.Btile[off];
    }
}

// ---------------------------------------------------------------------------
// Fused QKV GEMM (0..287) + bias table (288..2335) + late weight transposes
// (2336..3631).  wt blocks co-dispatched here (r11 verified ~free: this
// dispatch is VALU-bound, wt is HBM-latency-bound).  V projection writes
// directly transposed+key-permuted to vt (OUTMODE=2).
// ---------------------------------------------------------------------------
constexpr size_t kQkvSmem =
    sizeof(BiasSmem) > 35840 ? sizeof(BiasSmem) : 35840;

__global__ __launch_bounds__(256)
void qkv_bias_kernel(const ushort_t* __restrict__ A,
                     const ushort_t* wq, const ushort_t* wk, const ushort_t* wv,
                     const float* bq, const float* bk, const float* bv,
                     ushort_t* q, ushort_t* k, ushort_t* vt,
                     const float* __restrict__ sx, const float* __restrict__ sy,
                     const float* __restrict__ P1, const float* __restrict__ pb1,
                     const float* __restrict__ P2, const float* __restrict__ pb2,
                     ushort_t* __restrict__ biasb,
                     const float* __restrict__ Wo, const float* __restrict__ W1,
                     const float* __restrict__ W2,
                     ushort_t* woT, ushort_t* w1T, ushort_t* w2T)
{
    __shared__ __align__(16) char smem[kQkvSmem];
    const int bid = blockIdx.x;

    if (bid < 288) {
        const int z = bid / 96, rem = bid - z * 96;
        const int bx = rem % 6, by = rem / 6;
        if (z == 0)
            gemm_body<0, 1, 1>(A, wq, bq, q,  kD, kD,
                               by * 128, bx * 128, 0, kD, (ushort_t*)smem);
        else if (z == 1)
            gemm_body<0, 1, 1>(A, wk, bk, k,  kD, kD,
                               by * 128, bx * 128, 0, kD, (ushort_t*)smem);
        else
            gemm_body<0, 2, 1>(A, wv, bv, vt, kD, kD,
                               by * 128, bx * 128, 0, kD, (ushort_t*)smem);
    } else if (bid < 2336) {
        bias_body(bid - 288, *(BiasSmem*)smem, sx, sy, P1, pb1, P2, pb2, biasb);
    } else {
        float (*T)[65] = (float(*)[65])smem;
        const int t = bid - 2336;
        if (t < 144)      wt_tile(Wo, woT, kD,  kD,  (t % 12) * 64, (t / 12) * 64, T, threadIdx.x);
        else if (t < 720) { const int t2 = t - 144;
                            wt_tile(W1, w1T, kD,  kFF, (t2 % 12) * 64, (t2 / 12) * 64, T, threadIdx.x); }
        else              { const int t2 = t - 720;
                            wt_tile(W2, w2T, kFF, kD,  (t2 % 48) * 64, (t2 / 48) * 64, T, threadIdx.x); }
    }
}

// ---------------------------------------------------------------------------
// Pure attention kernel (1536 blocks).  V prefetched one t-iter ahead
// (r12) alongside K/bias.  Block = (b,h) x 16-q-row tile; 4 waves = 4
// K-quarters; 4-way in-block combine; swapped QK^T + lane-local softmax +
// permuted-V; bijective XCD swizzle (1536 = 8*192); no forced occupancy
// bound (r4 lesson).
// ---------------------------------------------------------------------------
__global__ __launch_bounds__(256)
void attn_kernel(const ushort_t* __restrict__ qg, const ushort_t* __restrict__ kg,
                 const ushort_t* __restrict__ vt, const ushort_t* __restrict__ biasb,
                 ushort_t* __restrict__ og)
{
    __shared__ __align__(16) AttnSmem S;
    const int bid = blockIdx.x;
    const int tid = threadIdx.x;

    const int swz  = (bid & 7) * 192 + (bid >> 3);
    const int bh   = swz >> 6;        // 0..23
    const int qt   = swz & 63;        // 16-row q tile index
    const int b  = bh / kNH, h = bh - b * kNH;
    const int z  = tid >> 6;          // wave = K quarter
    const int lane = tid & 63;
    const int fl = lane & 15, fq = lane >> 4;
    const int q0 = qt * 16;
    const int kbeg = z * 256;

    const size_t qoff = (size_t)(b * kL + q0 + fl) * kD + h * kDK + fq * 8;
    const bf16x8 aq0 = *(const bf16x8*)(qg + qoff);
    const bf16x8 aq1 = *(const bf16x8*)(qg + qoff + 32);

    const ushort_t* kbase = kg + (size_t)(b * kL) * kD + h * kDK + fq * 8;
    const ushort_t* vbase = vt + (size_t)(bh * 64) * kL + fq * 8;
    const ushort_t* btile = biasb +
        ((size_t)(bh * 64 + qt) * 16 + z * 4) * 1024 + lane * 16;

    f32x4 accO[4] = {};
    float l_loc = 0.f;                // lane-local l for q = q0+fl

    bf16x8 kc[4][2], vc[4][2];
    uint4 bc0, bc1;
    {
        #pragma unroll
        for (int n = 0; n < 4; ++n) {
            const ushort_t* kr = kbase + (size_t)(kbeg + n * 16 + fl) * kD;
            kc[n][0] = *(const bf16x8*)kr;
            kc[n][1] = *(const bf16x8*)(kr + 32);
            const ushort_t* vr = vbase + (size_t)(n * 16 + fl) * kL + kbeg;
            vc[n][0] = *(const bf16x8*)vr;
            vc[n][1] = *(const bf16x8*)(vr + 32);
        }
        bc0 = *(const uint4*)btile;
        bc1 = *(const uint4*)(btile + 8);
    }

    #pragma unroll
    for (int t = 0; t < 4; ++t) {
        const int k0 = kbeg + t * 64;

        // swapped QK^T: S^T[k][q] — A=K, B=Q (depends only on kc)
        f32x4 Sv[4] = {};
        __builtin_amdgcn_s_setprio(1);
        #pragma unroll
        for (int n = 0; n < 4; ++n) {
            Sv[n] = __builtin_amdgcn_mfma_f32_16x16x32_bf16(kc[n][0], aq0, Sv[n], 0, 0, 0);
            Sv[n] = __builtin_amdgcn_mfma_f32_16x16x32_bf16(kc[n][1], aq1, Sv[n], 0, 0, 0);
        }
        __builtin_amdgcn_s_setprio(0);

        // prefetch ALL of next iter (K, V, bias) — covered by exp + PV + next QK
        bf16x8 kn[4][2], vn[4][2];
        uint4 bn0, bn1;
        if (t < 3) {
            #pragma unroll
            for (int n = 0; n < 4; ++n) {
                const ushort_t* kr = kbase + (size_t)(k0 + 64 + n * 16 + fl) * kD;
                kn[n][0] = *(const bf16x8*)kr;
                kn[n][1] = *(const bf16x8*)(kr + 32);
                const ushort_t* vr = vbase + (size_t)(n * 16 + fl) * kL + k0 + 64;
                vn[n][0] = *(const bf16x8*)vr;
                vn[n][1] = *(const bf16x8*)(vr + 32);
            }
            bn0 = *(const uint4*)(btile + (t + 1) * 1024);
            bn1 = *(const uint4*)(btile + (t + 1) * 1024 + 8);
        }

        ushort_t bu[16];
        *(uint4*)&bu[0] = bc0;
        *(uint4*)&bu[8] = bc1;

        // lane-local softmax + lane-local P fragments (virtual-k ordering
        // matches vt's folded permutation)
        bf16x8 ap0, ap1;
        #pragma unroll
        for (int n = 0; n < 4; ++n)
            #pragma unroll
            for (int r = 0; r < 4; ++r) {
                const float e = __expf(fmaf(Sv[n][r], 0.125f, bf2f(bu[n * 4 + r])));
                l_loc += e;
                const short pb = (short)f2bf(e);
                if (n < 2) ap0[n * 4 + r] = pb;
                else       ap1[(n - 2) * 4 + r] = pb;
            }

        __builtin_amdgcn_s_setprio(1);
        #pragma unroll
        for (int n = 0; n < 4; ++n) {
            accO[n] = __builtin_amdgcn_mfma_f32_16x16x32_bf16(ap0, vc[n][0], accO[n], 0, 0, 0);
            accO[n] = __builtin_amdgcn_mfma_f32_16x16x32_bf16(ap1, vc[n][1], accO[n], 0, 0, 0);
        }
        __builtin_amdgcn_s_setprio(0);

        if (t < 3) {
            #pragma unroll
            for (int n = 0; n < 4; ++n) {
                kc[n][0] = kn[n][0]; kc[n][1] = kn[n][1];
                vc[n][0] = vn[n][0]; vc[n][1] = vn[n][1];
            }
            bc0 = bn0; bc1 = bn1;
        }
    }

    // full l for q=fl within this wave's K quarter: reduce across fq groups
    float l = l_loc;
    l += __shfl_xor(l, 16, 64);
    l += __shfl_xor(l, 32, 64);

    // inv for output rows q = fq*4+r (held by lane fq*4+r after reduction)
    float inv[4];
    #pragma unroll
    for (int r = 0; r < 4; ++r)
        inv[r] = 1.0f / __shfl(l, fq * 4 + r, 64);

    #pragma unroll
    for (int n = 0; n < 4; ++n)
        #pragma unroll
        for (int r = 0; r < 4; ++r)
            S.Ob[z][fq * 4 + r][n * 16 + fl] = f2bf(accO[n][r] * inv[r]);
    if (lane < 16) S.Ll[z][lane] = l;
    __syncthreads();

    if (tid < 128) {
        const int ri = tid >> 3;            // 0..15 (q row)
        const int d0 = (tid & 7) * 8;       // 8 cols each
        const float w0 = S.Ll[0][ri], w1 = S.Ll[1][ri];
        const float w2 = S.Ll[2][ri], w3 = S.Ll[3][ri];
        const float winv = 1.0f / (w0 + w1 + w2 + w3);
        const float c0 = w0 * winv, c1 = w1 * winv;
        const float c2 = w2 * winv, c3 = w3 * winv;

        ushort_t o[8];
        #pragma unroll
        for (int j = 0; j < 8; ++j)
            o[j] = f2bf(fmaf(c0, bf2f(S.Ob[0][ri][d0 + j]),
                        fmaf(c1, bf2f(S.Ob[1][ri][d0 + j]),
                        fmaf(c2, bf2f(S.Ob[2][ri][d0 + j]),
                             c3 * bf2f(S.Ob[3][ri][d0 + j])))));
        ushort_t* dp = og + (size_t)(b * kL + q0 + ri) * kD + h * kDK + d0;
        *(uint4*)dp = *(const uint4*)o;
    }
}

// ---------------------------------------------------------------------------
// Residual + split-K reduce + bias + LayerNorm.
// ---------------------------------------------------------------------------
template<int NPART, int DUAL>
__global__ __launch_bounds__(256)
void ln_kernel(const float* __restrict__ a, const float* __restrict__ parts,
               const float* __restrict__ bias,
               const float* __restrict__ g, const float* __restrict__ be,
               float* __restrict__ out, ushort_t* __restrict__ out_bf)
{
    const int row = blockIdx.x;
    const int tid = threadIdx.x;
    const float* pa = a + (size_t)row * kD;
    constexpr size_t NTOK = (size_t)kRows * kD;

    float v[3];
    float s = 0.f, sq = 0.f;
    #pragma unroll
    for (int i = 0; i < 3; ++i) {
        const int d = tid + i * 256;
        float t = pa[d] + bias[d];
        #pragma unroll
        for (int p = 0; p < NPART; ++p)
            t += parts[p * NTOK + (size_t)row * kD + d];
        v[i] = t;
        s  += t;
        sq += t * t;
    }
    #pragma unroll
    for (int off = 32; off > 0; off >>= 1) {
        s  += __shfl_down(s, off);
        sq += __shfl_down(sq, off);
    }
    __shared__ float bs[4], bq2[4];
    if ((tid & 63) == 0) { bs[tid >> 6] = s; bq2[tid >> 6] = sq; }
    __syncthreads();
    const float ts = bs[0] + bs[1] + bs[2] + bs[3];
    const float tq = bq2[0] + bq2[1] + bq2[2] + bq2[3];
    const float invn = 1.0f / (float)kD;
    const float mean = ts * invn;
    const float var  = tq * invn - mean * mean;
    const float rstd = rsqrtf(var + kEPS);

    float* po = out + (size_t)row * kD;
    #pragma unroll
    for (int i = 0; i < 3; ++i) {
        const int d = tid + i * 256;
        const float o = (v[i] - mean) * rstd * g[d] + be[d];
        po[d] = o;
        if (DUAL) out_bf[(size_t)row * kD + d] = f2bf(o);
    }
}

// ---------------------------------------------------------------------------
extern "C" void kernel_launch(void* const* d_in, const int* in_sizes, int n_in,
                              void* d_out, int out_size, void* d_ws, size_t ws_size,
                              hipStream_t stream)
{
    const float* src = (const float*)d_in[0];
    const float* sx  = (const float*)d_in[1];
    const float* sy  = (const float*)d_in[2];
    const float* Wq  = (const float*)d_in[3];  const float* bq  = (const float*)d_in[4];
    const float* Wk  = (const float*)d_in[5];  const float* bk  = (const float*)d_in[6];
    const float* Wv  = (const float*)d_in[7];  const float* bv  = (const float*)d_in[8];
    const float* Wo  = (const float*)d_in[9];  const float* bo  = (const float*)d_in[10];
    const float* P1  = (const float*)d_in[11]; const float* pb1 = (const float*)d_in[12];
    const float* P2  = (const float*)d_in[13]; const float* pb2 = (const float*)d_in[14];
    const float* W1  = (const float*)d_in[15]; const float* b1  = (const float*)d_in[16];
    const float* W2  = (const float*)d_in[17]; const float* b2  = (const float*)d_in[18];
    const float* g1  = (const float*)d_in[19]; const float* be1 = (const float*)d_in[20];
    const float* g2  = (const float*)d_in[21]; const float* be2 = (const float*)d_in[22];

    // ---- workspace arena (ushort units) ----
    constexpr size_t W768  = 768u * 768u;
    constexpr size_t W3072 = 768u * 3072u;
    constexpr size_t NTOK  = (size_t)kRows * kD;

    ushort_t* wsu = (ushort_t*)d_ws;
    ushort_t* wqT = wsu;
    ushort_t* wkT = wqT + W768;
    ushort_t* wvT = wkT + W768;
    ushort_t* qb  = wvT + W768;          // Q; dead after attn -> xbf
    ushort_t* kb  = qb + NTOK;
    ushort_t* vb  = kb + NTOK;           // (slot unused; V goes direct to vtb)
    ushort_t* sb  = vb + NTOK;           // src_bf -> attn out
    ushort_t* vtb = sb + NTOK;
    ushort_t* biasb = vtb + NTOK;        // 50 MB bias; dead after attn
    float*    xb    = (float*)(biasb + W768 + 2 * W3072);
    ushort_t* h1bf  = (ushort_t*)(xb + NTOK);
    ushort_t* xbf   = qb;

    const size_t h1off   = (size_t)(h1bf - wsu);
    const size_t bigNeed = (h1off + 20 * NTOK + W768 + 2 * W3072) * 2;
    const bool   big     = ws_size >= bigNeed;

    float*    s2p;
    float*    ff2p;
    ushort_t* scratch;
    int npWo, npFF;
    if (big) {
        s2p     = (float*)h1bf;
        ff2p    = (float*)(h1bf + 8 * NTOK);
        scratch = h1bf + 20 * NTOK;
        npWo = 4; npFF = 6;
    } else {
        s2p     = (float*)h1bf;
        ff2p    = (float*)(h1bf + 4 * NTOK);
        scratch = (ushort_t*)(ff2p + 3 * NTOK);
        npWo = 2; npFF = 3;
    }
    ushort_t* woT2 = scratch;
    ushort_t* w1T2 = woT2 + W768;
    ushort_t* w2T2 = w1T2 + W3072;

    const dim3 blk(256);

    // 1. early weight transposes + src->bf16 (fused)
    prep_kernel<<<dim3(1968), blk, 0, stream>>>(Wq, Wk, Wv, wqT, wkT, wvT, src, sb);

    // 2. QKV projection + bias table + late weight transposes (co-dispatched)
    qkv_bias_kernel<<<dim3(3632), blk, 0, stream>>>(
        sb, wqT, wkT, wvT, bq, bk, bv, qb, kb, vtb,
        sx, sy, P1, pb1, P2, pb2, biasb, Wo, W1, W2, woT2, w1T2, w2T2);

    // 3. pure attention (1536 blocks = 24 bh x 64 q-tiles, 4-way K-split)
    attn_kernel<<<dim3(1536), blk, 0, stream>>>(qb, kb, vtb, biasb, sb);

    // 4. out-projection, split-K -> fp32 partials
    gemm_splitk_kernel<<<dim3(kD / 128, kRows / 128, npWo), blk, 0, stream>>>(
        sb, woT2, s2p, kD, kD, kD / npWo);

    // 5. LN1: x = LN(src + bo + partials), fp32 + bf16
    if (big) ln_kernel<4, 1><<<dim3(kRows), blk, 0, stream>>>(src, s2p, bo, g1, be1, xb, xbf);
    else     ln_kernel<2, 1><<<dim3(kRows), blk, 0, stream>>>(src, s2p, bo, g1, be1, xb, xbf);

    // 6. FFN1: relu(x @ W1 + b1) -> bf16
    gemm_kernel<1, 1><<<dim3(kFF / 128, kRows / 128), blk, 0, stream>>>(
        xbf, w1T2, b1, h1bf, kFF, kD);

    // 7. FFN2, split-K -> fp32 partials
    gemm_splitk_kernel<<<dim3(kD / 128, kRows / 128, npFF), blk, 0, stream>>>(
        h1bf, w2T2, ff2p, kD, kFF, kFF / npFF);

    // 8. LN2: out = LN(x + b2 + partials)
    if (big) ln_kernel<6, 0><<<dim3(kRows), blk, 0, stream>>>(xb, ff2p, b2, g2, be2,
                                                              (float*)d_out, nullptr);
    else     ln_kernel<3, 0><<<dim3(kRows), blk, 0, stream>>>(xb, ff2p, b2, g2, be2,
                                                              (float*)d_out, nullptr);
}